// Round 4
// baseline (326.623 us; speedup 1.0000x reference)
//
#include <hip/hip_runtime.h>
#include <cstdint>
#include <cstddef>

#define BB 4
#define SS 2048
#define DD 1024
#define HH 16

typedef __bf16 bf16;
typedef __bf16 bf16x8 __attribute__((ext_vector_type(8)));
typedef __bf16 bf16x4 __attribute__((ext_vector_type(4)));
typedef float f32x4 __attribute__((ext_vector_type(4)));
typedef unsigned int u32;

typedef __attribute__((address_space(1))) const void* as1_cvoid;
typedef __attribute__((address_space(3))) void* as3_void;

__device__ __forceinline__ void gload_lds16(const void* g, void* l) {
  __builtin_amdgcn_global_load_lds((as1_cvoid)g, (as3_void)l, 16, 0, 0);
}

__device__ __forceinline__ u32 cvtpk(float lo, float hi) {
  u32 r;
  asm("v_cvt_pk_bf16_f32 %0, %1, %2" : "=v"(r) : "v"(lo), "v"(hi));
  return r;
}

// ---------------- K0: per-batch masked count ----------------
__global__ void mask_count_kernel(const unsigned char* __restrict__ mask, int* __restrict__ nm) {
  int wid = threadIdx.x >> 6, lane = threadIdx.x & 63;
  if (wid >= BB) return;
  int s = 0;
  for (int i = lane; i < SS; i += 64) s += (mask[wid * SS + i] != 0) ? 1 : 0;
#pragma unroll
  for (int m = 1; m < 64; m <<= 1) s += __shfl_xor(s, m);
  if (lane == 0) nm[wid] = s;
}

// ---------------- K1: f32 -> bf16 convert ----------------
__global__ void cvt_kernel(const float* __restrict__ src, bf16* __restrict__ dst, int n4) {
  int stride = gridDim.x * blockDim.x;
  for (int i = blockIdx.x * blockDim.x + threadIdx.x; i < n4; i += stride) {
    float4 v = ((const float4*)src)[i];
    bf16x4 o;
    o[0] = (bf16)v.x; o[1] = (bf16)v.y; o[2] = (bf16)v.z; o[3] = (bf16)v.w;
    ((bf16x4*)dst)[i] = o;
  }
}

// ---------------- K2: fused QKV GEMM: {Q,K,V}[M,1024] = X[M,1024] @ W{q,k,v}^T ----------------
__global__ void __launch_bounds__(256) gemm_qkv_kernel(const bf16* __restrict__ A,
                                                       const bf16* __restrict__ Wq,
                                                       const bf16* __restrict__ Wk,
                                                       const bf16* __restrict__ Wv,
                                                       bf16* __restrict__ Qo,
                                                       bf16* __restrict__ Ko,
                                                       bf16* __restrict__ Vo) {
  __shared__ bf16 Ab[128 * 32];
  __shared__ bf16 Bb[128 * 32];
  const int tid = threadIdx.x;
  const int wid = tid >> 6, lane = tid & 63;
  const int lr = lane & 15, lg = lane >> 4;
  const int K = DD, N = DD;
  const int nx = 24;  // 3 matrices x 8 N-tiles
  const int cpx = gridDim.x >> 3;
  const int lid = (blockIdx.x & 7) * cpx + (blockIdx.x >> 3);
  const int m0 = (lid / nx) * 128;
  const int ntile = lid % nx;
  const int which = ntile >> 3;
  const int n0 = (ntile & 7) * 128;
  const bf16* Bm = which == 0 ? Wq : (which == 1 ? Wk : Wv);
  bf16* Cout = which == 0 ? Qo : (which == 1 ? Ko : Vo);
  const int wm = (wid >> 1) * 64, wn = (wid & 1) * 64;
  f32x4 acc[4][4] = {};
  for (int k0 = 0; k0 < K; k0 += 32) {
    __syncthreads();
#pragma unroll
    for (int i = 0; i < 2; ++i) {
      int o = (wid * 2 + i) * 1024 + lane * 16;
      int row = o >> 6;
      int ke = (o & 63) >> 1;
      gload_lds16(A + (size_t)(m0 + row) * K + k0 + ke, (char*)Ab + o);
      gload_lds16(Bm + (size_t)(n0 + row) * K + k0 + ke, (char*)Bb + o);
    }
    __syncthreads();
    bf16x8 af[4], bf_[4];
#pragma unroll
    for (int i = 0; i < 4; ++i) af[i] = *(const bf16x8*)&Ab[(wm + i * 16 + lr) * 32 + lg * 8];
#pragma unroll
    for (int j = 0; j < 4; ++j) bf_[j] = *(const bf16x8*)&Bb[(wn + j * 16 + lr) * 32 + lg * 8];
#pragma unroll
    for (int i = 0; i < 4; ++i)
#pragma unroll
      for (int j = 0; j < 4; ++j)
        acc[i][j] = __builtin_amdgcn_mfma_f32_16x16x32_bf16(af[i], bf_[j], acc[i][j], 0, 0, 0);
  }
#pragma unroll
  for (int i = 0; i < 4; ++i)
#pragma unroll
    for (int j = 0; j < 4; ++j)
#pragma unroll
      for (int r = 0; r < 4; ++r) {
        int row = m0 + wm + i * 16 + lg * 4 + r;
        int col = n0 + wn + j * 16 + lr;
        Cout[(size_t)row * N + col] = (bf16)acc[i][j][r];
      }
}

// ---------------- K5: C[M,N] = A[M,K] @ B[N,K]^T (f32 out, for Wo) ----------------
__global__ void __launch_bounds__(256) gemm_bt_kernel(const bf16* __restrict__ A,
                                                      const bf16* __restrict__ Bm,
                                                      float* __restrict__ Cout,
                                                      int M, int N, int K) {
  __shared__ bf16 Ab[128 * 32];
  __shared__ bf16 Bb[128 * 32];
  const int tid = threadIdx.x;
  const int wid = tid >> 6, lane = tid & 63;
  const int lr = lane & 15, lg = lane >> 4;
  const int nx = N >> 7;
  const int cpx = gridDim.x >> 3;
  const int lid = (blockIdx.x & 7) * cpx + (blockIdx.x >> 3);
  const int m0 = (lid / nx) * 128, n0 = (lid % nx) * 128;
  const int wm = (wid >> 1) * 64, wn = (wid & 1) * 64;
  f32x4 acc[4][4] = {};
  for (int k0 = 0; k0 < K; k0 += 32) {
    __syncthreads();
#pragma unroll
    for (int i = 0; i < 2; ++i) {
      int o = (wid * 2 + i) * 1024 + lane * 16;
      int row = o >> 6;
      int ke = (o & 63) >> 1;
      gload_lds16(A + (size_t)(m0 + row) * K + k0 + ke, (char*)Ab + o);
      gload_lds16(Bm + (size_t)(n0 + row) * K + k0 + ke, (char*)Bb + o);
    }
    __syncthreads();
    bf16x8 af[4], bf_[4];
#pragma unroll
    for (int i = 0; i < 4; ++i) af[i] = *(const bf16x8*)&Ab[(wm + i * 16 + lr) * 32 + lg * 8];
#pragma unroll
    for (int j = 0; j < 4; ++j) bf_[j] = *(const bf16x8*)&Bb[(wn + j * 16 + lr) * 32 + lg * 8];
#pragma unroll
    for (int i = 0; i < 4; ++i)
#pragma unroll
      for (int j = 0; j < 4; ++j)
        acc[i][j] = __builtin_amdgcn_mfma_f32_16x16x32_bf16(af[i], bf_[j], acc[i][j], 0, 0, 0);
  }
#pragma unroll
  for (int i = 0; i < 4; ++i)
#pragma unroll
    for (int j = 0; j < 4; ++j)
#pragma unroll
      for (int r = 0; r < 4; ++r) {
        int row = m0 + wm + i * 16 + lg * 4 + r;
        int col = n0 + wn + j * 16 + lr;
        Cout[(size_t)row * N + col] = acc[i][j][r];
      }
}

// ---------------- K3: RoPE + RMSNorm + per-dim scale + V transpose ----------------
// Folds LOG2E^2 into q scale so attention softmax can use exp2f.
__global__ void __launch_bounds__(256) rope_rms_kernel(
    const bf16* __restrict__ Qraw, const bf16* __restrict__ Kraw, const bf16* __restrict__ Vraw,
    const float* __restrict__ qls, const float* __restrict__ kls, const float* __restrict__ pds,
    const int* __restrict__ nm,
    bf16* __restrict__ Qp, bf16* __restrict__ Kp, bf16* __restrict__ Vt) {
  __shared__ bf16 Vlds[64][72];
  const int s0 = blockIdx.x * 64;
  const int bh = blockIdx.y;
  const int b = bh >> 4, h = bh & 15;
  const int wid = threadIdx.x >> 6, l = threadIdx.x & 63;
  const int nmb = nm[b];
  const float qsc = qls[l] * 0.26017112262570096f * log1pf(__expf(pds[l]));
  const float ksc = kls[l];
  const float inv_ts = __expf((float)(l & 31) * (-9.210340371976184f / 32.0f));
  for (int i = 0; i < 16; ++i) {
    int s = s0 + wid * 16 + i;
    size_t off = ((size_t)(b * SS + s)) * DD + h * 64 + l;
    float q = (float)Qraw[off], k = (float)Kraw[off], v = (float)Vraw[off];
    float ang = (float)(s - nmb) * inv_ts;
    float sn, cs;
    sincosf(ang, &sn, &cs);
    float qo = __shfl_xor(q, 32), ko = __shfl_xor(k, 32);
    float qr = (l < 32) ? (q * cs - qo * sn) : (q * cs + qo * sn);
    float kr = (l < 32) ? (k * cs - ko * sn) : (k * cs + ko * sn);
    float sq = qr * qr, sk = kr * kr;
#pragma unroll
    for (int m = 1; m < 64; m <<= 1) {
      sq += __shfl_xor(sq, m);
      sk += __shfl_xor(sk, m);
    }
    float qout = qr * rsqrtf(sq * (1.0f / 64.0f) + 1e-6f) * qsc;
    float kout = kr * rsqrtf(sk * (1.0f / 64.0f) + 1e-6f) * ksc;
    size_t po = ((size_t)bh * SS + s) * 64 + l;
    Qp[po] = (bf16)qout;
    Kp[po] = (bf16)kout;
    Vlds[wid * 16 + i][l] = (bf16)v;
  }
  __syncthreads();
  int d = threadIdx.x >> 2, sc = (threadIdx.x & 3) * 16;
  bf16x8 v0, v1;
#pragma unroll
  for (int ii = 0; ii < 8; ++ii) v0[ii] = Vlds[sc + ii][d];
#pragma unroll
  for (int ii = 0; ii < 8; ++ii) v1[ii] = Vlds[sc + 8 + ii][d];
  size_t vo = ((size_t)bh * 64 + d) * SS + s0 + sc;
  *(bf16x8*)(Vt + vo) = v0;
  *(bf16x8*)(Vt + vo + 8) = v1;
}

// ---------------- K4: causal flash attention ----------------
// One 128-row q-strip per block (grid 1024, 4 blocks/CU). K double-buffered,
// V single-buffered with counted-vmcnt pipeline: V[t+1] staged after post-PV
// barrier, awaited via s_waitcnt vmcnt(2)+barrier before next PV (K prefetch
// stays in flight). Swapped QK^T, defer-max softmax, P via per-wave LDS.
__global__ void __launch_bounds__(256, 4) flash_kernel(
    const bf16* __restrict__ Qp, const bf16* __restrict__ Kp, const bf16* __restrict__ Vt,
    bf16* __restrict__ O, const int* __restrict__ nm) {
  __shared__ bf16 Kb[2][64 * 64];
  __shared__ bf16 Vb[64 * 64];
  __shared__ u32 Pl[4][16][36];
  const int cpx = gridDim.x >> 3;  // 128
  const int lid = (blockIdx.x & 7) * cpx + (blockIdx.x >> 3);
  const int bh = lid >> 4;
  const int jj = lid & 15;
  const int x = (jj & 1) ? (jj >> 1) : 15 - (jj >> 1);  // depth-alternating order
  const int b = bh >> 4, h = bh & 15;
  const int tid = threadIdx.x;
  const int wid = tid >> 6, lane = tid & 63;
  const int lr = lane & 15, lg = lane >> 4;
  const int nmb = nm[b];
  const int wq = x * 128 + wid * 32;
  const int nt = 2 * x + 2;

  // Q fragments (B-operand: col=q=lr, k=lg*8..+7)
  bf16x8 qf[2][2];
#pragma unroll
  for (int qi = 0; qi < 2; ++qi)
#pragma unroll
    for (int kh = 0; kh < 2; ++kh)
      qf[qi][kh] =
          *(const bf16x8*)(Qp + ((size_t)bh * SS + wq + qi * 16 + lr) * 64 + kh * 32 + lg * 8);

  float m_r[2] = {-1e30f, -1e30f};
  float l_p[2] = {0.f, 0.f};
  f32x4 o_acc[2][4] = {};

  auto STAGE_K = [&](int bi, int t) {
    const int kv0 = t * 64;
#pragma unroll
    for (int i = 0; i < 2; ++i) {
      int o = i * 4096 + tid * 16;
      int row = o >> 7;
      int c16 = ((o >> 4) & 7) ^ (row & 7);
      gload_lds16(Kp + ((size_t)bh * SS + kv0 + row) * 64 + c16 * 8, (char*)Kb[bi] + o);
    }
  };
  auto STAGE_V = [&](int t) {
    const int kv0 = t * 64;
#pragma unroll
    for (int i = 0; i < 2; ++i) {
      int o = i * 4096 + tid * 16;
      int row = o >> 7;
      int c16 = ((o >> 4) & 7) ^ (row & 7);
      gload_lds16(Vt + ((size_t)bh * 64 + row) * SS + kv0 + c16 * 8, (char*)Vb + o);
    }
  };

  STAGE_K(0, 0);
  STAGE_V(0);
  __syncthreads();
  int buf = 0;
  for (int t = 0; t < nt; ++t) {
    const int kv0 = t * 64;
    if (t + 1 < nt) STAGE_K(buf ^ 1, t + 1);  // K prefetch: in flight across barriers
    const bool active = (kv0 <= wq + 31);
    bf16x8 pb[2][2];
    if (active) {
#pragma unroll
      for (int qi = 0; qi < 2; ++qi) {
        f32x4 s[4];
#pragma unroll
        for (int j = 0; j < 4; ++j) {
          int row = j * 16 + lr;
          const char* kbase = (const char*)Kb[buf] + row * 128;
          bf16x8 kf0 = *(const bf16x8*)(kbase + ((lg ^ (row & 7)) << 4));
          bf16x8 kf1 = *(const bf16x8*)(kbase + (((4 + lg) ^ (row & 7)) << 4));
          f32x4 z = {};
          z = __builtin_amdgcn_mfma_f32_16x16x32_bf16(kf0, qf[qi][0], z, 0, 0, 0);
          z = __builtin_amdgcn_mfma_f32_16x16x32_bf16(kf1, qf[qi][1], z, 0, 0, 0);
          s[j] = z;
        }
        if (kv0 + 63 > wq) {  // causal mask (boundary tiles only)
          int qr = wq + qi * 16 + lr;
#pragma unroll
          for (int j = 0; j < 4; ++j) {
            int kvb = kv0 + j * 16 + lg * 4;
#pragma unroll
            for (int r = 0; r < 4; ++r)
              if (kvb + r > qr) s[j][r] = -1e30f;
          }
        }
        if (kv0 < nmb) {  // prefix-padding mask
#pragma unroll
          for (int j = 0; j < 4; ++j) {
            int kvb = kv0 + j * 16 + lg * 4;
#pragma unroll
            for (int r = 0; r < 4; ++r)
              if (kvb + r < nmb) s[j][r] = -1e30f;
          }
        }
        // per-lane partial max, max3-friendly tree
        float pm01 = fmaxf(fmaxf(s[0][0], s[0][1]), fmaxf(s[0][2], s[0][3]));
        float pm1 = fmaxf(fmaxf(s[1][0], s[1][1]), fmaxf(s[1][2], s[1][3]));
        float pm2 = fmaxf(fmaxf(s[2][0], s[2][1]), fmaxf(s[2][2], s[2][3]));
        float pm3 = fmaxf(fmaxf(s[3][0], s[3][1]), fmaxf(s[3][2], s[3][3]));
        float pm = fmaxf(fmaxf(pm01, pm1), fmaxf(pm2, pm3));
        // defer-max (exp2 domain, THR=8)
        if (!__all(pm - m_r[qi] <= 8.f)) {
          pm = fmaxf(pm, __shfl_xor(pm, 16));
          pm = fmaxf(pm, __shfl_xor(pm, 32));
          float mn = fmaxf(m_r[qi], pm);
          float scl = exp2f(m_r[qi] - mn);
          m_r[qi] = mn;
          l_p[qi] *= scl;
          f32x4 sv = {scl, scl, scl, scl};
#pragma unroll
          for (int jd = 0; jd < 4; ++jd) o_acc[qi][jd] *= sv;
        }
        const float mloc = m_r[qi];
        float lp = l_p[qi];
#pragma unroll
        for (int j = 0; j < 4; ++j) {
          float p0 = exp2f(s[j][0] - mloc), p1 = exp2f(s[j][1] - mloc);
          float p2 = exp2f(s[j][2] - mloc), p3 = exp2f(s[j][3] - mloc);
          lp += (p0 + p1) + (p2 + p3);
          uint2 w2;
          w2.x = cvtpk(p0, p1);
          w2.y = cvtpk(p2, p3);
          *(uint2*)&Pl[wid][lr][j * 8 + lg * 2] = w2;
        }
        l_p[qi] = lp;
#pragma unroll
        for (int kh = 0; kh < 2; ++kh)
          pb[qi][kh] = *(const bf16x8*)&Pl[wid][lr][kh * 16 + lg * 4];
      }
    }
    // ---- V[t] visibility: all waves' V loads complete (K[t+1] stays in flight) ----
    if (t > 0) {
      if (t + 1 < nt)
        asm volatile("s_waitcnt vmcnt(2)" ::: "memory");
      else
        asm volatile("s_waitcnt vmcnt(0)" ::: "memory");
      __builtin_amdgcn_s_barrier();
      __builtin_amdgcn_sched_barrier(0);
    }
    if (active) {
#pragma unroll
      for (int jd = 0; jd < 4; ++jd) {
        int row = jd * 16 + lr;
        const char* vbase = (const char*)Vb + row * 128;
        bf16x8 va0 = *(const bf16x8*)(vbase + ((lg ^ (row & 7)) << 4));
        bf16x8 va1 = *(const bf16x8*)(vbase + (((4 + lg) ^ (row & 7)) << 4));
        o_acc[0][jd] = __builtin_amdgcn_mfma_f32_16x16x32_bf16(va0, pb[0][0], o_acc[0][jd], 0, 0, 0);
        o_acc[0][jd] = __builtin_amdgcn_mfma_f32_16x16x32_bf16(va1, pb[0][1], o_acc[0][jd], 0, 0, 0);
        o_acc[1][jd] = __builtin_amdgcn_mfma_f32_16x16x32_bf16(va0, pb[1][0], o_acc[1][jd], 0, 0, 0);
        o_acc[1][jd] = __builtin_amdgcn_mfma_f32_16x16x32_bf16(va1, pb[1][1], o_acc[1][jd], 0, 0, 0);
      }
    }
    __syncthreads();  // PV reads of Vb done (all waves); drains K[t+1] too
    if (t + 1 < nt) STAGE_V(t + 1);
    buf ^= 1;
  }
  // ---- epilogue ----
#pragma unroll
  for (int qi = 0; qi < 2; ++qi) {
    float l = l_p[qi];
    l += __shfl_xor(l, 16);
    l += __shfl_xor(l, 32);
    float invl = 1.0f / l;
    size_t rowoff = ((size_t)b * SS + wq + qi * 16 + lr) * DD + h * 64;
#pragma unroll
    for (int jd = 0; jd < 4; ++jd) {
      f32x4 ov = o_acc[qi][jd] * invl;
      bf16x4 hv;
      hv[0] = (bf16)ov[0]; hv[1] = (bf16)ov[1]; hv[2] = (bf16)ov[2]; hv[3] = (bf16)ov[3];
      *(bf16x4*)(O + rowoff + jd * 16 + lg * 4) = hv;
    }
  }
}

// ---------------- host launch ----------------
extern "C" void kernel_launch(void* const* d_in, const int* in_sizes, int n_in,
                              void* d_out, int out_size, void* d_ws, size_t ws_size,
                              hipStream_t stream) {
  const float* X = (const float*)d_in[0];
  const float* Wq = (const float*)d_in[1];
  const float* Wk = (const float*)d_in[2];
  const float* Wv = (const float*)d_in[3];
  const float* Wo = (const float*)d_in[4];
  const float* qls = (const float*)d_in[5];
  const float* kls = (const float*)d_in[6];
  const float* pds = (const float*)d_in[7];
  const unsigned char* mask = (const unsigned char*)d_in[8];

  char* ws = (char*)d_ws;
  size_t off = 0;
  auto alloc = [&](size_t bytes) {
    char* p = ws + off;
    off += (bytes + 255) & ~(size_t)255;
    return p;
  };
  const size_t NTOK = (size_t)BB * SS;  // 8192
  int* nm = (int*)alloc(16);
  bf16* Xb = (bf16*)alloc(NTOK * DD * 2);
  bf16* Wqb = (bf16*)alloc((size_t)DD * DD * 2);
  bf16* Wkb = (bf16*)alloc((size_t)DD * DD * 2);
  bf16* Wvb = (bf16*)alloc((size_t)DD * DD * 2);
  bf16* Wob = (bf16*)alloc((size_t)DD * DD * 2);
  bf16* Qraw = (bf16*)alloc(NTOK * DD * 2);
  bf16* Kraw = (bf16*)alloc(NTOK * DD * 2);
  bf16* Vraw = (bf16*)alloc(NTOK * DD * 2);
  bf16* Kp = (bf16*)alloc(NTOK * DD * 2);
  bf16* Vt = (bf16*)alloc(NTOK * DD * 2);
  bf16* Qp = Xb;     // alias: Xb dead after QKV GEMM
  bf16* Oat = Qraw;  // alias: Qraw dead after rope kernel

  mask_count_kernel<<<1, 256, 0, stream>>>(mask, nm);
  cvt_kernel<<<1024, 256, 0, stream>>>(X, Xb, (int)(NTOK * DD / 4));
  cvt_kernel<<<256, 256, 0, stream>>>(Wq, Wqb, DD * DD / 4);
  cvt_kernel<<<256, 256, 0, stream>>>(Wk, Wkb, DD * DD / 4);
  cvt_kernel<<<256, 256, 0, stream>>>(Wv, Wvb, DD * DD / 4);
  cvt_kernel<<<256, 256, 0, stream>>>(Wo, Wob, DD * DD / 4);

  gemm_qkv_kernel<<<(int)(NTOK / 128) * 24, 256, 0, stream>>>(Xb, Wqb, Wkb, Wvb, Qraw, Kraw,
                                                              Vraw);
  rope_rms_kernel<<<dim3(SS / 64, BB * HH), 256, 0, stream>>>(Qraw, Kraw, Vraw, qls, kls, pds,
                                                              nm, Qp, Kp, Vt);
  flash_kernel<<<1024, 256, 0, stream>>>(Qp, Kp, Vt, Oat, nm);
  gemm_bt_kernel<<<(int)(NTOK / 128) * (DD / 128), 256, 0, stream>>>(Oat, Wob, (float*)d_out,
                                                                     (int)NTOK, DD, DD);
}

// Round 5
// 276.852 us; speedup vs baseline: 1.1798x; 1.1798x over previous
//
#include <hip/hip_runtime.h>
#include <cstdint>
#include <cstddef>

#define BB 4
#define SS 2048
#define DD 1024
#define HH 16

typedef __bf16 bf16;
typedef __bf16 bf16x8 __attribute__((ext_vector_type(8)));
typedef __bf16 bf16x4 __attribute__((ext_vector_type(4)));
typedef float f32x4 __attribute__((ext_vector_type(4)));
typedef unsigned int u32;

typedef __attribute__((address_space(1))) const void* as1_cvoid;
typedef __attribute__((address_space(3))) void* as3_void;

__device__ __forceinline__ void gload_lds16(const void* g, void* l) {
  __builtin_amdgcn_global_load_lds((as1_cvoid)g, (as3_void)l, 16, 0, 0);
}

__device__ __forceinline__ u32 cvtpk(float lo, float hi) {
  u32 r;
  asm("v_cvt_pk_bf16_f32 %0, %1, %2" : "=v"(r) : "v"(lo), "v"(hi));
  return r;
}

// ---------------- K0: per-batch masked count ----------------
__global__ void mask_count_kernel(const unsigned char* __restrict__ mask, int* __restrict__ nm) {
  int wid = threadIdx.x >> 6, lane = threadIdx.x & 63;
  if (wid >= BB) return;
  int s = 0;
  for (int i = lane; i < SS; i += 64) s += (mask[wid * SS + i] != 0) ? 1 : 0;
#pragma unroll
  for (int m = 1; m < 64; m <<= 1) s += __shfl_xor(s, m);
  if (lane == 0) nm[wid] = s;
}

// ---------------- K1: f32 -> bf16 convert ----------------
__global__ void cvt_kernel(const float* __restrict__ src, bf16* __restrict__ dst, int n4) {
  int stride = gridDim.x * blockDim.x;
  for (int i = blockIdx.x * blockDim.x + threadIdx.x; i < n4; i += stride) {
    float4 v = ((const float4*)src)[i];
    bf16x4 o;
    o[0] = (bf16)v.x; o[1] = (bf16)v.y; o[2] = (bf16)v.z; o[3] = (bf16)v.w;
    ((bf16x4*)dst)[i] = o;
  }
}

// ---------------- K2: fused QKV GEMM: {Q,K,V}[M,1024] = X[M,1024] @ W{q,k,v}^T ----------------
__global__ void __launch_bounds__(256) gemm_qkv_kernel(const bf16* __restrict__ A,
                                                       const bf16* __restrict__ Wq,
                                                       const bf16* __restrict__ Wk,
                                                       const bf16* __restrict__ Wv,
                                                       bf16* __restrict__ Qo,
                                                       bf16* __restrict__ Ko,
                                                       bf16* __restrict__ Vo) {
  __shared__ bf16 Ab[128 * 32];
  __shared__ bf16 Bb[128 * 32];
  const int tid = threadIdx.x;
  const int wid = tid >> 6, lane = tid & 63;
  const int lr = lane & 15, lg = lane >> 4;
  const int K = DD, N = DD;
  const int nx = 24;  // 3 matrices x 8 N-tiles
  const int cpx = gridDim.x >> 3;
  const int lid = (blockIdx.x & 7) * cpx + (blockIdx.x >> 3);
  const int m0 = (lid / nx) * 128;
  const int ntile = lid % nx;
  const int which = ntile >> 3;
  const int n0 = (ntile & 7) * 128;
  const bf16* Bm = which == 0 ? Wq : (which == 1 ? Wk : Wv);
  bf16* Cout = which == 0 ? Qo : (which == 1 ? Ko : Vo);
  const int wm = (wid >> 1) * 64, wn = (wid & 1) * 64;
  f32x4 acc[4][4] = {};
  for (int k0 = 0; k0 < K; k0 += 32) {
    __syncthreads();
#pragma unroll
    for (int i = 0; i < 2; ++i) {
      int o = (wid * 2 + i) * 1024 + lane * 16;
      int row = o >> 6;
      int ke = (o & 63) >> 1;
      gload_lds16(A + (size_t)(m0 + row) * K + k0 + ke, (char*)Ab + o);
      gload_lds16(Bm + (size_t)(n0 + row) * K + k0 + ke, (char*)Bb + o);
    }
    __syncthreads();
    bf16x8 af[4], bf_[4];
#pragma unroll
    for (int i = 0; i < 4; ++i) af[i] = *(const bf16x8*)&Ab[(wm + i * 16 + lr) * 32 + lg * 8];
#pragma unroll
    for (int j = 0; j < 4; ++j) bf_[j] = *(const bf16x8*)&Bb[(wn + j * 16 + lr) * 32 + lg * 8];
#pragma unroll
    for (int i = 0; i < 4; ++i)
#pragma unroll
      for (int j = 0; j < 4; ++j)
        acc[i][j] = __builtin_amdgcn_mfma_f32_16x16x32_bf16(af[i], bf_[j], acc[i][j], 0, 0, 0);
  }
#pragma unroll
  for (int i = 0; i < 4; ++i)
#pragma unroll
    for (int j = 0; j < 4; ++j)
#pragma unroll
      for (int r = 0; r < 4; ++r) {
        int row = m0 + wm + i * 16 + lg * 4 + r;
        int col = n0 + wn + j * 16 + lr;
        Cout[(size_t)row * N + col] = (bf16)acc[i][j][r];
      }
}

// ---------------- K5: C[M,N] = A[M,K] @ B[N,K]^T (f32 out, for Wo) ----------------
__global__ void __launch_bounds__(256) gemm_bt_kernel(const bf16* __restrict__ A,
                                                      const bf16* __restrict__ Bm,
                                                      float* __restrict__ Cout,
                                                      int M, int N, int K) {
  __shared__ bf16 Ab[128 * 32];
  __shared__ bf16 Bb[128 * 32];
  const int tid = threadIdx.x;
  const int wid = tid >> 6, lane = tid & 63;
  const int lr = lane & 15, lg = lane >> 4;
  const int nx = N >> 7;
  const int cpx = gridDim.x >> 3;
  const int lid = (blockIdx.x & 7) * cpx + (blockIdx.x >> 3);
  const int m0 = (lid / nx) * 128, n0 = (lid % nx) * 128;
  const int wm = (wid >> 1) * 64, wn = (wid & 1) * 64;
  f32x4 acc[4][4] = {};
  for (int k0 = 0; k0 < K; k0 += 32) {
    __syncthreads();
#pragma unroll
    for (int i = 0; i < 2; ++i) {
      int o = (wid * 2 + i) * 1024 + lane * 16;
      int row = o >> 6;
      int ke = (o & 63) >> 1;
      gload_lds16(A + (size_t)(m0 + row) * K + k0 + ke, (char*)Ab + o);
      gload_lds16(Bm + (size_t)(n0 + row) * K + k0 + ke, (char*)Bb + o);
    }
    __syncthreads();
    bf16x8 af[4], bf_[4];
#pragma unroll
    for (int i = 0; i < 4; ++i) af[i] = *(const bf16x8*)&Ab[(wm + i * 16 + lr) * 32 + lg * 8];
#pragma unroll
    for (int j = 0; j < 4; ++j) bf_[j] = *(const bf16x8*)&Bb[(wn + j * 16 + lr) * 32 + lg * 8];
#pragma unroll
    for (int i = 0; i < 4; ++i)
#pragma unroll
      for (int j = 0; j < 4; ++j)
        acc[i][j] = __builtin_amdgcn_mfma_f32_16x16x32_bf16(af[i], bf_[j], acc[i][j], 0, 0, 0);
  }
#pragma unroll
  for (int i = 0; i < 4; ++i)
#pragma unroll
    for (int j = 0; j < 4; ++j)
#pragma unroll
      for (int r = 0; r < 4; ++r) {
        int row = m0 + wm + i * 16 + lg * 4 + r;
        int col = n0 + wn + j * 16 + lr;
        Cout[(size_t)row * N + col] = acc[i][j][r];
      }
}

// ---------------- K3: RoPE + RMSNorm + per-dim scale + V transpose ----------------
// Folds LOG2E^2 into q scale so attention softmax can use exp2f.
__global__ void __launch_bounds__(256) rope_rms_kernel(
    const bf16* __restrict__ Qraw, const bf16* __restrict__ Kraw, const bf16* __restrict__ Vraw,
    const float* __restrict__ qls, const float* __restrict__ kls, const float* __restrict__ pds,
    const int* __restrict__ nm,
    bf16* __restrict__ Qp, bf16* __restrict__ Kp, bf16* __restrict__ Vt) {
  __shared__ bf16 Vlds[64][72];
  const int s0 = blockIdx.x * 64;
  const int bh = blockIdx.y;
  const int b = bh >> 4, h = bh & 15;
  const int wid = threadIdx.x >> 6, l = threadIdx.x & 63;
  const int nmb = nm[b];
  const float qsc = qls[l] * 0.26017112262570096f * log1pf(__expf(pds[l]));
  const float ksc = kls[l];
  const float inv_ts = __expf((float)(l & 31) * (-9.210340371976184f / 32.0f));
  for (int i = 0; i < 16; ++i) {
    int s = s0 + wid * 16 + i;
    size_t off = ((size_t)(b * SS + s)) * DD + h * 64 + l;
    float q = (float)Qraw[off], k = (float)Kraw[off], v = (float)Vraw[off];
    float ang = (float)(s - nmb) * inv_ts;
    float sn, cs;
    sincosf(ang, &sn, &cs);
    float qo = __shfl_xor(q, 32), ko = __shfl_xor(k, 32);
    float qr = (l < 32) ? (q * cs - qo * sn) : (q * cs + qo * sn);
    float kr = (l < 32) ? (k * cs - ko * sn) : (k * cs + ko * sn);
    float sq = qr * qr, sk = kr * kr;
#pragma unroll
    for (int m = 1; m < 64; m <<= 1) {
      sq += __shfl_xor(sq, m);
      sk += __shfl_xor(sk, m);
    }
    float qout = qr * rsqrtf(sq * (1.0f / 64.0f) + 1e-6f) * qsc;
    float kout = kr * rsqrtf(sk * (1.0f / 64.0f) + 1e-6f) * ksc;
    size_t po = ((size_t)bh * SS + s) * 64 + l;
    Qp[po] = (bf16)qout;
    Kp[po] = (bf16)kout;
    Vlds[wid * 16 + i][l] = (bf16)v;
  }
  __syncthreads();
  int d = threadIdx.x >> 2, sc = (threadIdx.x & 3) * 16;
  bf16x8 v0, v1;
#pragma unroll
  for (int ii = 0; ii < 8; ++ii) v0[ii] = Vlds[sc + ii][d];
#pragma unroll
  for (int ii = 0; ii < 8; ++ii) v1[ii] = Vlds[sc + 8 + ii][d];
  size_t vo = ((size_t)bh * 64 + d) * SS + s0 + sc;
  *(bf16x8*)(Vt + vo) = v0;
  *(bf16x8*)(Vt + vo + 8) = v1;
}

// ---------------- K4: causal flash attention ----------------
// One 128-row q-strip per block (grid 1024, target 4 blocks/CU). K double-
// buffered, V single-buffered with counted-vmcnt pipeline. Swapped QK^T,
// defer-max softmax, P via per-wave LDS. launch_bounds(256,2): VGPR cap ~128
// (cap ~ 256/min_waves empirically; (256,4) forced 64 -> massive spill in R4).
__global__ void __launch_bounds__(256, 2) flash_kernel(
    const bf16* __restrict__ Qp, const bf16* __restrict__ Kp, const bf16* __restrict__ Vt,
    bf16* __restrict__ O, const int* __restrict__ nm) {
  __shared__ bf16 Kb[2][64 * 64];
  __shared__ bf16 Vb[64 * 64];
  __shared__ u32 Pl[4][16][36];
  const int cpx = gridDim.x >> 3;  // 128
  const int lid = (blockIdx.x & 7) * cpx + (blockIdx.x >> 3);
  const int bh = lid >> 4;
  const int jj = lid & 15;
  const int x = (jj & 1) ? (jj >> 1) : 15 - (jj >> 1);  // depth-alternating order
  const int b = bh >> 4, h = bh & 15;
  const int tid = threadIdx.x;
  const int wid = tid >> 6, lane = tid & 63;
  const int lr = lane & 15, lg = lane >> 4;
  const int nmb = nm[b];
  const int wq = x * 128 + wid * 32;
  const int nt = 2 * x + 2;

  // Q fragments (B-operand: col=q=lr, k=lg*8..+7)
  bf16x8 qf[2][2];
#pragma unroll
  for (int qi = 0; qi < 2; ++qi)
#pragma unroll
    for (int kh = 0; kh < 2; ++kh)
      qf[qi][kh] =
          *(const bf16x8*)(Qp + ((size_t)bh * SS + wq + qi * 16 + lr) * 64 + kh * 32 + lg * 8);

  float m_r[2] = {-1e30f, -1e30f};
  float l_p[2] = {0.f, 0.f};
  f32x4 o_acc[2][4] = {};

  auto STAGE_K = [&](int bi, int t) {
    const int kv0 = t * 64;
#pragma unroll
    for (int i = 0; i < 2; ++i) {
      int o = i * 4096 + tid * 16;
      int row = o >> 7;
      int c16 = ((o >> 4) & 7) ^ (row & 7);
      gload_lds16(Kp + ((size_t)bh * SS + kv0 + row) * 64 + c16 * 8, (char*)Kb[bi] + o);
    }
  };
  auto STAGE_V = [&](int t) {
    const int kv0 = t * 64;
#pragma unroll
    for (int i = 0; i < 2; ++i) {
      int o = i * 4096 + tid * 16;
      int row = o >> 7;
      int c16 = ((o >> 4) & 7) ^ (row & 7);
      gload_lds16(Vt + ((size_t)bh * 64 + row) * SS + kv0 + c16 * 8, (char*)Vb + o);
    }
  };

  STAGE_K(0, 0);
  STAGE_V(0);
  __syncthreads();
  int buf = 0;
  for (int t = 0; t < nt; ++t) {
    const int kv0 = t * 64;
    if (t + 1 < nt) STAGE_K(buf ^ 1, t + 1);  // K prefetch overlaps QK^T+softmax
    const bool active = (kv0 <= wq + 31);
    bf16x8 pb[2][2];
    if (active) {
      __builtin_amdgcn_s_setprio(1);
#pragma unroll
      for (int qi = 0; qi < 2; ++qi) {
        f32x4 s[4];
#pragma unroll
        for (int j = 0; j < 4; ++j) {
          int row = j * 16 + lr;
          const char* kbase = (const char*)Kb[buf] + row * 128;
          bf16x8 kf0 = *(const bf16x8*)(kbase + ((lg ^ (row & 7)) << 4));
          bf16x8 kf1 = *(const bf16x8*)(kbase + (((4 + lg) ^ (row & 7)) << 4));
          f32x4 z = {};
          z = __builtin_amdgcn_mfma_f32_16x16x32_bf16(kf0, qf[qi][0], z, 0, 0, 0);
          z = __builtin_amdgcn_mfma_f32_16x16x32_bf16(kf1, qf[qi][1], z, 0, 0, 0);
          s[j] = z;
        }
        __builtin_amdgcn_s_setprio(0);
        if (kv0 + 63 > wq) {  // causal mask (boundary tiles only)
          int qr = wq + qi * 16 + lr;
#pragma unroll
          for (int j = 0; j < 4; ++j) {
            int kvb = kv0 + j * 16 + lg * 4;
#pragma unroll
            for (int r = 0; r < 4; ++r)
              if (kvb + r > qr) s[j][r] = -1e30f;
          }
        }
        if (kv0 < nmb) {  // prefix-padding mask
#pragma unroll
          for (int j = 0; j < 4; ++j) {
            int kvb = kv0 + j * 16 + lg * 4;
#pragma unroll
            for (int r = 0; r < 4; ++r)
              if (kvb + r < nmb) s[j][r] = -1e30f;
          }
        }
        // per-lane partial max
        float pm0 = fmaxf(fmaxf(s[0][0], s[0][1]), fmaxf(s[0][2], s[0][3]));
        float pm1 = fmaxf(fmaxf(s[1][0], s[1][1]), fmaxf(s[1][2], s[1][3]));
        float pm2 = fmaxf(fmaxf(s[2][0], s[2][1]), fmaxf(s[2][2], s[2][3]));
        float pm3 = fmaxf(fmaxf(s[3][0], s[3][1]), fmaxf(s[3][2], s[3][3]));
        float pm = fmaxf(fmaxf(pm0, pm1), fmaxf(pm2, pm3));
        // defer-max (exp2 domain, THR=8)
        if (!__all(pm - m_r[qi] <= 8.f)) {
          pm = fmaxf(pm, __shfl_xor(pm, 16));
          pm = fmaxf(pm, __shfl_xor(pm, 32));
          float mn = fmaxf(m_r[qi], pm);
          float scl = exp2f(m_r[qi] - mn);
          m_r[qi] = mn;
          l_p[qi] *= scl;
          f32x4 sv = {scl, scl, scl, scl};
#pragma unroll
          for (int jd = 0; jd < 4; ++jd) o_acc[qi][jd] *= sv;
        }
        const float mloc = m_r[qi];
        float lp = l_p[qi];
#pragma unroll
        for (int j = 0; j < 4; ++j) {
          float p0 = exp2f(s[j][0] - mloc), p1 = exp2f(s[j][1] - mloc);
          float p2 = exp2f(s[j][2] - mloc), p3 = exp2f(s[j][3] - mloc);
          lp += (p0 + p1) + (p2 + p3);
          uint2 w2;
          w2.x = cvtpk(p0, p1);
          w2.y = cvtpk(p2, p3);
          *(uint2*)&Pl[wid][lr][j * 8 + lg * 2] = w2;
        }
        l_p[qi] = lp;
#pragma unroll
        for (int kh = 0; kh < 2; ++kh)
          pb[qi][kh] = *(const bf16x8*)&Pl[wid][lr][kh * 16 + lg * 4];
        __builtin_amdgcn_s_setprio(1);
      }
      __builtin_amdgcn_s_setprio(0);
    }
    // ---- V[t] visibility: all waves' V loads complete (K[t+1] stays in flight) ----
    if (t > 0) {
      if (t + 1 < nt)
        asm volatile("s_waitcnt vmcnt(2)" ::: "memory");
      else
        asm volatile("s_waitcnt vmcnt(0)" ::: "memory");
      __builtin_amdgcn_s_barrier();
      __builtin_amdgcn_sched_barrier(0);
    }
    if (active) {
      __builtin_amdgcn_s_setprio(1);
#pragma unroll
      for (int jd = 0; jd < 4; ++jd) {
        int row = jd * 16 + lr;
        const char* vbase = (const char*)Vb + row * 128;
        bf16x8 va0 = *(const bf16x8*)(vbase + ((lg ^ (row & 7)) << 4));
        bf16x8 va1 = *(const bf16x8*)(vbase + (((4 + lg) ^ (row & 7)) << 4));
        o_acc[0][jd] = __builtin_amdgcn_mfma_f32_16x16x32_bf16(va0, pb[0][0], o_acc[0][jd], 0, 0, 0);
        o_acc[0][jd] = __builtin_amdgcn_mfma_f32_16x16x32_bf16(va1, pb[0][1], o_acc[0][jd], 0, 0, 0);
        o_acc[1][jd] = __builtin_amdgcn_mfma_f32_16x16x32_bf16(va0, pb[1][0], o_acc[1][jd], 0, 0, 0);
        o_acc[1][jd] = __builtin_amdgcn_mfma_f32_16x16x32_bf16(va1, pb[1][1], o_acc[1][jd], 0, 0, 0);
      }
      __builtin_amdgcn_s_setprio(0);
    }
    __syncthreads();  // PV reads of Vb done (all waves); drains K[t+1] too
    if (t + 1 < nt) STAGE_V(t + 1);
    buf ^= 1;
  }
  // ---- epilogue ----
#pragma unroll
  for (int qi = 0; qi < 2; ++qi) {
    float l = l_p[qi];
    l += __shfl_xor(l, 16);
    l += __shfl_xor(l, 32);
    float invl = 1.0f / l;
    size_t rowoff = ((size_t)b * SS + wq + qi * 16 + lr) * DD + h * 64;
#pragma unroll
    for (int jd = 0; jd < 4; ++jd) {
      f32x4 ov = o_acc[qi][jd] * invl;
      bf16x4 hv;
      hv[0] = (bf16)ov[0]; hv[1] = (bf16)ov[1]; hv[2] = (bf16)ov[2]; hv[3] = (bf16)ov[3];
      *(bf16x4*)(O + rowoff + jd * 16 + lg * 4) = hv;
    }
  }
}

// ---------------- host launch ----------------
extern "C" void kernel_launch(void* const* d_in, const int* in_sizes, int n_in,
                              void* d_out, int out_size, void* d_ws, size_t ws_size,
                              hipStream_t stream) {
  const float* X = (const float*)d_in[0];
  const float* Wq = (const float*)d_in[1];
  const float* Wk = (const float*)d_in[2];
  const float* Wv = (const float*)d_in[3];
  const float* Wo = (const float*)d_in[4];
  const float* qls = (const float*)d_in[5];
  const float* kls = (const float*)d_in[6];
  const float* pds = (const float*)d_in[7];
  const unsigned char* mask = (const unsigned char*)d_in[8];

  char* ws = (char*)d_ws;
  size_t off = 0;
  auto alloc = [&](size_t bytes) {
    char* p = ws + off;
    off += (bytes + 255) & ~(size_t)255;
    return p;
  };
  const size_t NTOK = (size_t)BB * SS;  // 8192
  int* nm = (int*)alloc(16);
  bf16* Xb = (bf16*)alloc(NTOK * DD * 2);
  bf16* Wqb = (bf16*)alloc((size_t)DD * DD * 2);
  bf16* Wkb = (bf16*)alloc((size_t)DD * DD * 2);
  bf16* Wvb = (bf16*)alloc((size_t)DD * DD * 2);
  bf16* Wob = (bf16*)alloc((size_t)DD * DD * 2);
  bf16* Qraw = (bf16*)alloc(NTOK * DD * 2);
  bf16* Kraw = (bf16*)alloc(NTOK * DD * 2);
  bf16* Vraw = (bf16*)alloc(NTOK * DD * 2);
  bf16* Kp = (bf16*)alloc(NTOK * DD * 2);
  bf16* Vt = (bf16*)alloc(NTOK * DD * 2);
  bf16* Qp = Xb;     // alias: Xb dead after QKV GEMM
  bf16* Oat = Qraw;  // alias: Qraw dead after rope kernel

  mask_count_kernel<<<1, 256, 0, stream>>>(mask, nm);
  cvt_kernel<<<1024, 256, 0, stream>>>(X, Xb, (int)(NTOK * DD / 4));
  cvt_kernel<<<256, 256, 0, stream>>>(Wq, Wqb, DD * DD / 4);
  cvt_kernel<<<256, 256, 0, stream>>>(Wk, Wkb, DD * DD / 4);
  cvt_kernel<<<256, 256, 0, stream>>>(Wv, Wvb, DD * DD / 4);
  cvt_kernel<<<256, 256, 0, stream>>>(Wo, Wob, DD * DD / 4);

  gemm_qkv_kernel<<<(int)(NTOK / 128) * 24, 256, 0, stream>>>(Xb, Wqb, Wkb, Wvb, Qraw, Kraw,
                                                              Vraw);
  rope_rms_kernel<<<dim3(SS / 64, BB * HH), 256, 0, stream>>>(Qraw, Kraw, Vraw, qls, kls, pds,
                                                              nm, Qp, Kp, Vt);
  flash_kernel<<<1024, 256, 0, stream>>>(Qp, Kp, Vt, Oat, nm);
  gemm_bt_kernel<<<(int)(NTOK / 128) * (DD / 128), 256, 0, stream>>>(Oat, Wob, (float*)d_out,
                                                                     (int)NTOK, DD, DD);
}

// Round 6
// 243.897 us; speedup vs baseline: 1.3392x; 1.1351x over previous
//
#include <hip/hip_runtime.h>
#include <cstdint>
#include <cstddef>

#define BB 4
#define SS 2048
#define DD 1024
#define HH 16

typedef __bf16 bf16;
typedef __bf16 bf16x8 __attribute__((ext_vector_type(8)));
typedef __bf16 bf16x4 __attribute__((ext_vector_type(4)));
typedef float f32x4 __attribute__((ext_vector_type(4)));
typedef unsigned int u32;

typedef __attribute__((address_space(1))) const void* as1_cvoid;
typedef __attribute__((address_space(3))) void* as3_void;

__device__ __forceinline__ void gload_lds16(const void* g, void* l) {
  __builtin_amdgcn_global_load_lds((as1_cvoid)g, (as3_void)l, 16, 0, 0);
}

__device__ __forceinline__ u32 cvtpk(float lo, float hi) {
  u32 r;
  asm("v_cvt_pk_bf16_f32 %0, %1, %2" : "=v"(r) : "v"(lo), "v"(hi));
  return r;
}

// ---------------- K0: per-batch masked count ----------------
__global__ void mask_count_kernel(const unsigned char* __restrict__ mask, int* __restrict__ nm) {
  int wid = threadIdx.x >> 6, lane = threadIdx.x & 63;
  if (wid >= BB) return;
  int s = 0;
  for (int i = lane; i < SS; i += 64) s += (mask[wid * SS + i] != 0) ? 1 : 0;
#pragma unroll
  for (int m = 1; m < 64; m <<= 1) s += __shfl_xor(s, m);
  if (lane == 0) nm[wid] = s;
}

// ---------------- K1: f32 -> bf16 convert ----------------
__global__ void cvt_kernel(const float* __restrict__ src, bf16* __restrict__ dst, int n4) {
  int stride = gridDim.x * blockDim.x;
  for (int i = blockIdx.x * blockDim.x + threadIdx.x; i < n4; i += stride) {
    float4 v = ((const float4*)src)[i];
    bf16x4 o;
    o[0] = (bf16)v.x; o[1] = (bf16)v.y; o[2] = (bf16)v.z; o[3] = (bf16)v.w;
    ((bf16x4*)dst)[i] = o;
  }
}

// ---------------- K2: fused QKV GEMM ----------------
__global__ void __launch_bounds__(256) gemm_qkv_kernel(const bf16* __restrict__ A,
                                                       const bf16* __restrict__ Wq,
                                                       const bf16* __restrict__ Wk,
                                                       const bf16* __restrict__ Wv,
                                                       bf16* __restrict__ Qo,
                                                       bf16* __restrict__ Ko,
                                                       bf16* __restrict__ Vo) {
  __shared__ bf16 Ab[128 * 32];
  __shared__ bf16 Bb[128 * 32];
  const int tid = threadIdx.x;
  const int wid = tid >> 6, lane = tid & 63;
  const int lr = lane & 15, lg = lane >> 4;
  const int K = DD, N = DD;
  const int nx = 24;  // 3 matrices x 8 N-tiles
  const int cpx = gridDim.x >> 3;
  const int lid = (blockIdx.x & 7) * cpx + (blockIdx.x >> 3);
  const int m0 = (lid / nx) * 128;
  const int ntile = lid % nx;
  const int which = ntile >> 3;
  const int n0 = (ntile & 7) * 128;
  const bf16* Bm = which == 0 ? Wq : (which == 1 ? Wk : Wv);
  bf16* Cout = which == 0 ? Qo : (which == 1 ? Ko : Vo);
  const int wm = (wid >> 1) * 64, wn = (wid & 1) * 64;
  f32x4 acc[4][4] = {};
  for (int k0 = 0; k0 < K; k0 += 32) {
    __syncthreads();
#pragma unroll
    for (int i = 0; i < 2; ++i) {
      int o = (wid * 2 + i) * 1024 + lane * 16;
      int row = o >> 6;
      int ke = (o & 63) >> 1;
      gload_lds16(A + (size_t)(m0 + row) * K + k0 + ke, (char*)Ab + o);
      gload_lds16(Bm + (size_t)(n0 + row) * K + k0 + ke, (char*)Bb + o);
    }
    __syncthreads();
    bf16x8 af[4], bf_[4];
#pragma unroll
    for (int i = 0; i < 4; ++i) af[i] = *(const bf16x8*)&Ab[(wm + i * 16 + lr) * 32 + lg * 8];
#pragma unroll
    for (int j = 0; j < 4; ++j) bf_[j] = *(const bf16x8*)&Bb[(wn + j * 16 + lr) * 32 + lg * 8];
#pragma unroll
    for (int i = 0; i < 4; ++i)
#pragma unroll
      for (int j = 0; j < 4; ++j)
        acc[i][j] = __builtin_amdgcn_mfma_f32_16x16x32_bf16(af[i], bf_[j], acc[i][j], 0, 0, 0);
  }
#pragma unroll
  for (int i = 0; i < 4; ++i)
#pragma unroll
    for (int j = 0; j < 4; ++j)
#pragma unroll
      for (int r = 0; r < 4; ++r) {
        int row = m0 + wm + i * 16 + lg * 4 + r;
        int col = n0 + wn + j * 16 + lr;
        Cout[(size_t)row * N + col] = (bf16)acc[i][j][r];
      }
}

// ---------------- K5: C[M,N] = A[M,K] @ B[N,K]^T (f32 out, for Wo) ----------------
__global__ void __launch_bounds__(256) gemm_bt_kernel(const bf16* __restrict__ A,
                                                      const bf16* __restrict__ Bm,
                                                      float* __restrict__ Cout,
                                                      int M, int N, int K) {
  __shared__ bf16 Ab[128 * 32];
  __shared__ bf16 Bb[128 * 32];
  const int tid = threadIdx.x;
  const int wid = tid >> 6, lane = tid & 63;
  const int lr = lane & 15, lg = lane >> 4;
  const int nx = N >> 7;
  const int cpx = gridDim.x >> 3;
  const int lid = (blockIdx.x & 7) * cpx + (blockIdx.x >> 3);
  const int m0 = (lid / nx) * 128, n0 = (lid % nx) * 128;
  const int wm = (wid >> 1) * 64, wn = (wid & 1) * 64;
  f32x4 acc[4][4] = {};
  for (int k0 = 0; k0 < K; k0 += 32) {
    __syncthreads();
#pragma unroll
    for (int i = 0; i < 2; ++i) {
      int o = (wid * 2 + i) * 1024 + lane * 16;
      int row = o >> 6;
      int ke = (o & 63) >> 1;
      gload_lds16(A + (size_t)(m0 + row) * K + k0 + ke, (char*)Ab + o);
      gload_lds16(Bm + (size_t)(n0 + row) * K + k0 + ke, (char*)Bb + o);
    }
    __syncthreads();
    bf16x8 af[4], bf_[4];
#pragma unroll
    for (int i = 0; i < 4; ++i) af[i] = *(const bf16x8*)&Ab[(wm + i * 16 + lr) * 32 + lg * 8];
#pragma unroll
    for (int j = 0; j < 4; ++j) bf_[j] = *(const bf16x8*)&Bb[(wn + j * 16 + lr) * 32 + lg * 8];
#pragma unroll
    for (int i = 0; i < 4; ++i)
#pragma unroll
      for (int j = 0; j < 4; ++j)
        acc[i][j] = __builtin_amdgcn_mfma_f32_16x16x32_bf16(af[i], bf_[j], acc[i][j], 0, 0, 0);
  }
#pragma unroll
  for (int i = 0; i < 4; ++i)
#pragma unroll
    for (int j = 0; j < 4; ++j)
#pragma unroll
      for (int r = 0; r < 4; ++r) {
        int row = m0 + wm + i * 16 + lg * 4 + r;
        int col = n0 + wn + j * 16 + lr;
        Cout[(size_t)row * N + col] = acc[i][j][r];
      }
}

// ---------------- K3: RoPE + RMSNorm + per-dim scale + V transpose ----------------
__global__ void __launch_bounds__(256) rope_rms_kernel(
    const bf16* __restrict__ Qraw, const bf16* __restrict__ Kraw, const bf16* __restrict__ Vraw,
    const float* __restrict__ qls, const float* __restrict__ kls, const float* __restrict__ pds,
    const int* __restrict__ nm,
    bf16* __restrict__ Qp, bf16* __restrict__ Kp, bf16* __restrict__ Vt) {
  __shared__ bf16 Vlds[64][72];
  const int s0 = blockIdx.x * 64;
  const int bh = blockIdx.y;
  const int b = bh >> 4, h = bh & 15;
  const int wid = threadIdx.x >> 6, l = threadIdx.x & 63;
  const int nmb = nm[b];
  const float qsc = qls[l] * 0.26017112262570096f * log1pf(__expf(pds[l]));
  const float ksc = kls[l];
  const float inv_ts = __expf((float)(l & 31) * (-9.210340371976184f / 32.0f));
  for (int i = 0; i < 16; ++i) {
    int s = s0 + wid * 16 + i;
    size_t off = ((size_t)(b * SS + s)) * DD + h * 64 + l;
    float q = (float)Qraw[off], k = (float)Kraw[off], v = (float)Vraw[off];
    float ang = (float)(s - nmb) * inv_ts;
    float sn, cs;
    sincosf(ang, &sn, &cs);
    float qo = __shfl_xor(q, 32), ko = __shfl_xor(k, 32);
    float qr = (l < 32) ? (q * cs - qo * sn) : (q * cs + qo * sn);
    float kr = (l < 32) ? (k * cs - ko * sn) : (k * cs + ko * sn);
    float sq = qr * qr, sk = kr * kr;
#pragma unroll
    for (int m = 1; m < 64; m <<= 1) {
      sq += __shfl_xor(sq, m);
      sk += __shfl_xor(sk, m);
    }
    float qout = qr * rsqrtf(sq * (1.0f / 64.0f) + 1e-6f) * qsc;
    float kout = kr * rsqrtf(sk * (1.0f / 64.0f) + 1e-6f) * ksc;
    size_t po = ((size_t)bh * SS + s) * 64 + l;
    Qp[po] = (bf16)qout;
    Kp[po] = (bf16)kout;
    Vlds[wid * 16 + i][l] = (bf16)v;
  }
  __syncthreads();
  int d = threadIdx.x >> 2, sc = (threadIdx.x & 3) * 16;
  bf16x8 v0, v1;
#pragma unroll
  for (int ii = 0; ii < 8; ++ii) v0[ii] = Vlds[sc + ii][d];
#pragma unroll
  for (int ii = 0; ii < 8; ++ii) v1[ii] = Vlds[sc + 8 + ii][d];
  size_t vo = ((size_t)bh * 64 + d) * SS + s0 + sc;
  *(bf16x8*)(Vt + vo) = v0;
  *(bf16x8*)(Vt + vo + 8) = v1;
}

// ---------------- K4: causal flash attention, wave-paired 64-row strips ----------------
// Block = 4 waves; each wave owns 16 q-rows of strip A (xA=31-px) and 16 of strip B
// (xB=px). Every block = 33 strip-tile units (uniform), shares K/V staging AND kf/vf
// LDS reads between strips. LDS 33.8K -> 4 blocks/CU; grid 1024 -> exactly 4/CU.
// px bit-reversed so co-resident blocks mix loop lengths. Counted-vmcnt V pipeline.
__global__ void __launch_bounds__(256, 2) flash_kernel(
    const bf16* __restrict__ Qp, const bf16* __restrict__ Kp, const bf16* __restrict__ Vt,
    bf16* __restrict__ O, const int* __restrict__ nm) {
  __shared__ bf16 Kb[2][64 * 64];
  __shared__ bf16 Vb[64 * 64];
  __shared__ u32 Pl[4][16][36];
  const int cpx = gridDim.x >> 3;  // 128
  const int lid = (blockIdx.x & 7) * cpx + (blockIdx.x >> 3);
  const int bh = lid >> 4;
  const int j4 = lid & 15;
  const int px = ((j4 & 1) << 3) | ((j4 & 2) << 1) | ((j4 & 4) >> 1) | ((j4 & 8) >> 3);
  const int xA = 31 - px, xB = px;
  const int b = bh >> 4, h = bh & 15;
  const int tid = threadIdx.x;
  const int wid = tid >> 6, lane = tid & 63;
  const int lr = lane & 15, lg = lane >> 4;
  const int nmb = nm[b];
  const int wqA = xA * 64 + wid * 16;
  const int wqB = xB * 64 + wid * 16;
  const int nt = xA + 1;  // strip A is the deeper one

  // Q fragments (B-operand: col=q=lr, k=lg*8..+7), 16 rows per wave per strip
  bf16x8 qfA[2], qfB[2];
#pragma unroll
  for (int kh = 0; kh < 2; ++kh) {
    qfA[kh] = *(const bf16x8*)(Qp + ((size_t)bh * SS + wqA + lr) * 64 + kh * 32 + lg * 8);
    qfB[kh] = *(const bf16x8*)(Qp + ((size_t)bh * SS + wqB + lr) * 64 + kh * 32 + lg * 8);
  }

  float mA = -1e30f, lA = 0.f, mB = -1e30f, lB = 0.f;
  f32x4 oA[4] = {}, oB[4] = {};

  auto STAGE_K = [&](int bi, int t) {
    const int kv0 = t * 64;
#pragma unroll
    for (int i = 0; i < 2; ++i) {
      int o = i * 4096 + tid * 16;
      int row = o >> 7;
      int c16 = ((o >> 4) & 7) ^ (row & 7);
      gload_lds16(Kp + ((size_t)bh * SS + kv0 + row) * 64 + c16 * 8, (char*)Kb[bi] + o);
    }
  };
  auto STAGE_V = [&](int t) {
    const int kv0 = t * 64;
#pragma unroll
    for (int i = 0; i < 2; ++i) {
      int o = i * 4096 + tid * 16;
      int row = o >> 7;
      int c16 = ((o >> 4) & 7) ^ (row & 7);
      gload_lds16(Vt + ((size_t)bh * 64 + row) * SS + kv0 + c16 * 8, (char*)Vb + o);
    }
  };

  STAGE_K(0, 0);
  STAGE_V(0);
  __syncthreads();
  int buf = 0;
  for (int t = 0; t < nt; ++t) {
    const int kv0 = t * 64;
    if (t + 1 < nt) STAGE_K(buf ^ 1, t + 1);  // stays in flight across V-barrier
    const bool actB = (t <= xB);
    bf16x8 pbA[2], pbB[2];

    // ---- per-strip: QK^T -> softmax -> P fragment (shares Kb reads via compiler CSE) ----
    auto DO_STRIP = [&](const bf16x8* qf, float& m_r, float& l_pp, f32x4* oacc,
                        bf16x8* pb, int xS, int wqS) {
      f32x4 s[4];
      __builtin_amdgcn_s_setprio(1);
#pragma unroll
      for (int j = 0; j < 4; ++j) {
        int row = j * 16 + lr;
        const char* kbase = (const char*)Kb[buf] + row * 128;
        bf16x8 kf0 = *(const bf16x8*)(kbase + ((lg ^ (row & 7)) << 4));
        bf16x8 kf1 = *(const bf16x8*)(kbase + (((4 + lg) ^ (row & 7)) << 4));
        f32x4 z = {};
        z = __builtin_amdgcn_mfma_f32_16x16x32_bf16(kf0, qf[0], z, 0, 0, 0);
        z = __builtin_amdgcn_mfma_f32_16x16x32_bf16(kf1, qf[1], z, 0, 0, 0);
        s[j] = z;
      }
      __builtin_amdgcn_s_setprio(0);
      if (t == xS) {  // causal boundary tile
        int qr = wqS + lr;
#pragma unroll
        for (int j = 0; j < 4; ++j) {
          int kvb = kv0 + j * 16 + lg * 4;
#pragma unroll
          for (int r = 0; r < 4; ++r)
            if (kvb + r > qr) s[j][r] = -1e30f;
        }
      }
      if (kv0 < nmb) {  // prefix-padding mask
#pragma unroll
        for (int j = 0; j < 4; ++j) {
          int kvb = kv0 + j * 16 + lg * 4;
#pragma unroll
          for (int r = 0; r < 4; ++r)
            if (kvb + r < nmb) s[j][r] = -1e30f;
        }
      }
      float pm0 = fmaxf(fmaxf(s[0][0], s[0][1]), fmaxf(s[0][2], s[0][3]));
      float pm1 = fmaxf(fmaxf(s[1][0], s[1][1]), fmaxf(s[1][2], s[1][3]));
      float pm2 = fmaxf(fmaxf(s[2][0], s[2][1]), fmaxf(s[2][2], s[2][3]));
      float pm3 = fmaxf(fmaxf(s[3][0], s[3][1]), fmaxf(s[3][2], s[3][3]));
      float pm = fmaxf(fmaxf(pm0, pm1), fmaxf(pm2, pm3));
      if (!__all(pm - m_r <= 8.f)) {  // defer-max (exp2 domain, THR=8)
        pm = fmaxf(pm, __shfl_xor(pm, 16));
        pm = fmaxf(pm, __shfl_xor(pm, 32));
        float mn = fmaxf(m_r, pm);
        float scl = exp2f(m_r - mn);
        m_r = mn;
        l_pp *= scl;
        f32x4 sv = {scl, scl, scl, scl};
#pragma unroll
        for (int jd = 0; jd < 4; ++jd) oacc[jd] *= sv;
      }
      const float mloc = m_r;
      float lp = l_pp;
#pragma unroll
      for (int j = 0; j < 4; ++j) {
        float p0 = exp2f(s[j][0] - mloc), p1 = exp2f(s[j][1] - mloc);
        float p2 = exp2f(s[j][2] - mloc), p3 = exp2f(s[j][3] - mloc);
        lp += (p0 + p1) + (p2 + p3);
        uint2 w2;
        w2.x = cvtpk(p0, p1);
        w2.y = cvtpk(p2, p3);
        *(uint2*)&Pl[wid][lr][j * 8 + lg * 2] = w2;
      }
      l_pp = lp;
#pragma unroll
      for (int kh = 0; kh < 2; ++kh) pb[kh] = *(const bf16x8*)&Pl[wid][lr][kh * 16 + lg * 4];
    };

    DO_STRIP(qfA, mA, lA, oA, pbA, xA, wqA);
    if (actB) DO_STRIP(qfB, mB, lB, oB, pbB, xB, wqB);

    // ---- V[t] visibility (own V writes done; K[t+1] stays in flight) ----
    if (t > 0) {
      if (t + 1 < nt)
        asm volatile("s_waitcnt vmcnt(2)" ::: "memory");
      else
        asm volatile("s_waitcnt vmcnt(0)" ::: "memory");
      __builtin_amdgcn_s_barrier();
      __builtin_amdgcn_sched_barrier(0);
    }
    // ---- PV (A = Vt tile rows=d, B = P cols=q); vf reads shared between strips ----
    __builtin_amdgcn_s_setprio(1);
#pragma unroll
    for (int jd = 0; jd < 4; ++jd) {
      int row = jd * 16 + lr;
      const char* vbase = (const char*)Vb + row * 128;
      bf16x8 va0 = *(const bf16x8*)(vbase + ((lg ^ (row & 7)) << 4));
      bf16x8 va1 = *(const bf16x8*)(vbase + (((4 + lg) ^ (row & 7)) << 4));
      oA[jd] = __builtin_amdgcn_mfma_f32_16x16x32_bf16(va0, pbA[0], oA[jd], 0, 0, 0);
      oA[jd] = __builtin_amdgcn_mfma_f32_16x16x32_bf16(va1, pbA[1], oA[jd], 0, 0, 0);
      if (actB) {
        oB[jd] = __builtin_amdgcn_mfma_f32_16x16x32_bf16(va0, pbB[0], oB[jd], 0, 0, 0);
        oB[jd] = __builtin_amdgcn_mfma_f32_16x16x32_bf16(va1, pbB[1], oB[jd], 0, 0, 0);
      }
    }
    __builtin_amdgcn_s_setprio(0);
    __syncthreads();  // all waves done with Vb (and Kb[buf])
    if (t + 1 < nt) STAGE_V(t + 1);
    buf ^= 1;
  }
  // ---- epilogue: reduce deferred l across lane-groups, normalize, store ----
#pragma unroll
  for (int st = 0; st < 2; ++st) {
    float l = st == 0 ? lA : lB;
    const f32x4* oacc = st == 0 ? oA : oB;
    int wq = st == 0 ? wqA : wqB;
    l += __shfl_xor(l, 16);
    l += __shfl_xor(l, 32);
    float invl = 1.0f / l;
    size_t rowoff = ((size_t)b * SS + wq + lr) * DD + h * 64;
#pragma unroll
    for (int jd = 0; jd < 4; ++jd) {
      f32x4 ov = oacc[jd] * invl;
      bf16x4 hv;
      hv[0] = (bf16)ov[0]; hv[1] = (bf16)ov[1]; hv[2] = (bf16)ov[2]; hv[3] = (bf16)ov[3];
      *(bf16x4*)(O + rowoff + jd * 16 + lg * 4) = hv;
    }
  }
}

// ---------------- host launch ----------------
extern "C" void kernel_launch(void* const* d_in, const int* in_sizes, int n_in,
                              void* d_out, int out_size, void* d_ws, size_t ws_size,
                              hipStream_t stream) {
  const float* X = (const float*)d_in[0];
  const float* Wq = (const float*)d_in[1];
  const float* Wk = (const float*)d_in[2];
  const float* Wv = (const float*)d_in[3];
  const float* Wo = (const float*)d_in[4];
  const float* qls = (const float*)d_in[5];
  const float* kls = (const float*)d_in[6];
  const float* pds = (const float*)d_in[7];
  const unsigned char* mask = (const unsigned char*)d_in[8];

  char* ws = (char*)d_ws;
  size_t off = 0;
  auto alloc = [&](size_t bytes) {
    char* p = ws + off;
    off += (bytes + 255) & ~(size_t)255;
    return p;
  };
  const size_t NTOK = (size_t)BB * SS;  // 8192
  int* nm = (int*)alloc(16);
  bf16* Xb = (bf16*)alloc(NTOK * DD * 2);
  bf16* Wqb = (bf16*)alloc((size_t)DD * DD * 2);
  bf16* Wkb = (bf16*)alloc((size_t)DD * DD * 2);
  bf16* Wvb = (bf16*)alloc((size_t)DD * DD * 2);
  bf16* Wob = (bf16*)alloc((size_t)DD * DD * 2);
  bf16* Qraw = (bf16*)alloc(NTOK * DD * 2);
  bf16* Kraw = (bf16*)alloc(NTOK * DD * 2);
  bf16* Vraw = (bf16*)alloc(NTOK * DD * 2);
  bf16* Kp = (bf16*)alloc(NTOK * DD * 2);
  bf16* Vt = (bf16*)alloc(NTOK * DD * 2);
  bf16* Qp = Xb;     // alias: Xb dead after QKV GEMM
  bf16* Oat = Qraw;  // alias: Qraw dead after rope kernel

  mask_count_kernel<<<1, 256, 0, stream>>>(mask, nm);
  cvt_kernel<<<1024, 256, 0, stream>>>(X, Xb, (int)(NTOK * DD / 4));
  cvt_kernel<<<256, 256, 0, stream>>>(Wq, Wqb, DD * DD / 4);
  cvt_kernel<<<256, 256, 0, stream>>>(Wk, Wkb, DD * DD / 4);
  cvt_kernel<<<256, 256, 0, stream>>>(Wv, Wvb, DD * DD / 4);
  cvt_kernel<<<256, 256, 0, stream>>>(Wo, Wob, DD * DD / 4);

  gemm_qkv_kernel<<<(int)(NTOK / 128) * 24, 256, 0, stream>>>(Xb, Wqb, Wkb, Wvb, Qraw, Kraw,
                                                              Vraw);
  rope_rms_kernel<<<dim3(SS / 64, BB * HH), 256, 0, stream>>>(Qraw, Kraw, Vraw, qls, kls, pds,
                                                              nm, Qp, Kp, Vt);
  flash_kernel<<<1024, 256, 0, stream>>>(Qp, Kp, Vt, Oat, nm);
  gemm_bt_kernel<<<(int)(NTOK / 128) * (DD / 128), 256, 0, stream>>>(Oat, Wob, (float*)d_out,
                                                                     (int)NTOK, DD, DD);
}

// Round 7
// 203.911 us; speedup vs baseline: 1.6018x; 1.1961x over previous
//
#include <hip/hip_runtime.h>
#include <cstdint>
#include <cstddef>

#define BB 4
#define SS 2048
#define DD 1024
#define HH 16

typedef __bf16 bf16;
typedef __bf16 bf16x8 __attribute__((ext_vector_type(8)));
typedef __bf16 bf16x4 __attribute__((ext_vector_type(4)));
typedef float f32x4 __attribute__((ext_vector_type(4)));
typedef unsigned int u32;

typedef __attribute__((address_space(1))) const void* as1_cvoid;
typedef __attribute__((address_space(3))) void* as3_void;

__device__ __forceinline__ void gload_lds16(const void* g, void* l) {
  __builtin_amdgcn_global_load_lds((as1_cvoid)g, (as3_void)l, 16, 0, 0);
}

// ---------------- K0: per-batch masked count ----------------
__global__ void mask_count_kernel(const unsigned char* __restrict__ mask, int* __restrict__ nm) {
  int wid = threadIdx.x >> 6, lane = threadIdx.x & 63;
  if (wid >= BB) return;
  int s = 0;
  for (int i = lane; i < SS; i += 64) s += (mask[wid * SS + i] != 0) ? 1 : 0;
#pragma unroll
  for (int m = 1; m < 64; m <<= 1) s += __shfl_xor(s, m);
  if (lane == 0) nm[wid] = s;
}

// ---------------- K1: f32 -> bf16 convert ----------------
__global__ void cvt_kernel(const float* __restrict__ src, bf16* __restrict__ dst, int n4) {
  int stride = gridDim.x * blockDim.x;
  for (int i = blockIdx.x * blockDim.x + threadIdx.x; i < n4; i += stride) {
    float4 v = ((const float4*)src)[i];
    bf16x4 o;
    o[0] = (bf16)v.x; o[1] = (bf16)v.y; o[2] = (bf16)v.z; o[3] = (bf16)v.w;
    ((bf16x4*)dst)[i] = o;
  }
}

// ---------------- K1b: RoPE sin/cos table: tbl[b*S+s][j] = (cos,sin)((s-nm[b])*ts_j) ----------------
__global__ void sincos_table_kernel(const int* __restrict__ nm, float2* __restrict__ tbl) {
  int idx = blockIdx.x * 256 + threadIdx.x;  // b*S+s, 8192 total
  int b = idx >> 11, s = idx & 2047;
  int pos = s - nm[b];
  float2* row = tbl + (size_t)idx * 32;
  for (int j = 0; j < 32; ++j) {
    float inv_ts = __expf((float)j * (-9.210340371976184f / 32.0f));  // 10000^{-j/32}
    float sn, cs;
    sincosf((float)pos * inv_ts, &sn, &cs);
    row[j] = make_float2(cs, sn);
  }
}

// ---------------- K2: fused QKV GEMM + RoPE/RMS/scale epilogue ----------------
// {Q,K,V} = X @ W^T; Q/K: rope (table) -> rmsnorm -> scale, written [B,H,S,64];
// V: transposed via LDS, written [B,H,64,S]. Folds LOG2E^2/8*softplus into q scale.
__global__ void __launch_bounds__(256) gemm_qkv_kernel(
    const bf16* __restrict__ A, const bf16* __restrict__ Wq, const bf16* __restrict__ Wk,
    const bf16* __restrict__ Wv, const float* __restrict__ qls, const float* __restrict__ kls,
    const float* __restrict__ pds, const float2* __restrict__ tbl,
    bf16* __restrict__ Qp, bf16* __restrict__ Kp, bf16* __restrict__ Vt) {
  __shared__ __align__(16) char smem[4 * 64 * 72 * 2];  // staging (16K) U transpose (36K)
  bf16* Ab = (bf16*)smem;
  bf16* Bb = (bf16*)(smem + 8192);
  const int tid = threadIdx.x;
  const int wid = tid >> 6, lane = tid & 63;
  const int lr = lane & 15, lg = lane >> 4;
  const int K = DD;
  const int nx = 24;  // 3 matrices x 8 N-tiles
  const int cpx = gridDim.x >> 3;
  const int lid = (blockIdx.x & 7) * cpx + (blockIdx.x >> 3);
  const int m0 = (lid / nx) * 128;
  const int ntile = lid % nx;
  const int which = ntile >> 3;
  const int n0 = (ntile & 7) * 128;
  const bf16* Bm = which == 0 ? Wq : (which == 1 ? Wk : Wv);
  const int wm = (wid >> 1) * 64, wn = (wid & 1) * 64;
  f32x4 acc[4][4] = {};
  for (int k0 = 0; k0 < K; k0 += 32) {
    __syncthreads();
#pragma unroll
    for (int i = 0; i < 2; ++i) {
      int o = (wid * 2 + i) * 1024 + lane * 16;
      int row = o >> 6;
      int ke = (o & 63) >> 1;
      gload_lds16(A + (size_t)(m0 + row) * K + k0 + ke, (char*)Ab + o);
      gload_lds16(Bm + (size_t)(n0 + row) * K + k0 + ke, (char*)Bb + o);
    }
    __syncthreads();
    bf16x8 af[4], bf_[4];
#pragma unroll
    for (int i = 0; i < 4; ++i) af[i] = *(const bf16x8*)&Ab[(wm + i * 16 + lr) * 32 + lg * 8];
#pragma unroll
    for (int j = 0; j < 4; ++j) bf_[j] = *(const bf16x8*)&Bb[(wn + j * 16 + lr) * 32 + lg * 8];
#pragma unroll
    for (int i = 0; i < 4; ++i)
#pragma unroll
      for (int j = 0; j < 4; ++j)
        acc[i][j] = __builtin_amdgcn_mfma_f32_16x16x32_bf16(af[i], bf_[j], acc[i][j], 0, 0, 0);
  }
  const int b = m0 >> 11;
  const int s0g = m0 & 2047;
  const int hq = n0 >> 6;  // first of 2 heads in this N-tile
  if (which < 2) {
    // ---- Q/K epilogue: rope -> rms -> scale, write [B,H,S,64] ----
    float scj[4];
#pragma unroll
    for (int j = 0; j < 4; ++j) {
      int d = j * 16 + lr;
      scj[j] = (which == 0) ? qls[d] * 0.26017112262570096f * log1pf(__expf(pds[d]))
                            : kls[d];
    }
    bf16* Out = which == 0 ? Qp : Kp;
    const int h = hq + (wn >> 6);
    const size_t base = (size_t)(b * 16 + h) * SS;
#pragma unroll
    for (int i = 0; i < 4; ++i)
#pragma unroll
      for (int r = 0; r < 4; ++r) {
        int srow = s0g + wm + i * 16 + lg * 4 + r;
        const float2* trow = tbl + ((size_t)(b * SS + srow) << 5);
        float2 t0 = trow[lr], t1 = trow[16 + lr];
        float a0 = acc[i][0][r], a1 = acc[i][1][r], a2 = acc[i][2][r], a3 = acc[i][3][r];
        float n0_ = a0 * t0.x - a2 * t0.y;
        float n2_ = a2 * t0.x + a0 * t0.y;
        float n1_ = a1 * t1.x - a3 * t1.y;
        float n3_ = a3 * t1.x + a1 * t1.y;
        float ssum = n0_ * n0_ + n1_ * n1_ + n2_ * n2_ + n3_ * n3_;
        ssum += __shfl_xor(ssum, 1);
        ssum += __shfl_xor(ssum, 2);
        ssum += __shfl_xor(ssum, 4);
        ssum += __shfl_xor(ssum, 8);
        float rinv = rsqrtf(ssum * (1.0f / 64.0f) + 1e-6f);
        bf16* orow = Out + (base + srow) * 64;
        orow[lr]      = (bf16)(n0_ * rinv * scj[0]);
        orow[16 + lr] = (bf16)(n1_ * rinv * scj[1]);
        orow[32 + lr] = (bf16)(n2_ * rinv * scj[2]);
        orow[48 + lr] = (bf16)(n3_ * rinv * scj[3]);
      }
  } else {
    // ---- V epilogue: transpose via LDS (reuse staging region), write [B,H,64,S] ----
    __syncthreads();  // all MFMA LDS reads done; safe to reuse smem
    bf16* tw = (bf16*)smem + wid * 64 * 72;  // per-wave [64 d][72 s-padded]
#pragma unroll
    for (int i = 0; i < 4; ++i)
#pragma unroll
      for (int j = 0; j < 4; ++j)
#pragma unroll
        for (int r = 0; r < 4; ++r)
          tw[(j * 16 + lr) * 72 + i * 16 + lg * 4 + r] = (bf16)acc[i][j][r];
    __syncthreads();
    int d = tid >> 2, sc = (tid & 3) * 16;
#pragma unroll
    for (int w = 0; w < 4; ++w) {
      int rh = w >> 1, hh = w & 1;
      const bf16* ts = (const bf16*)smem + w * 64 * 72 + d * 72 + sc;
      bf16x8 v0 = *(const bf16x8*)ts;
      bf16x8 v1 = *(const bf16x8*)(ts + 8);
      size_t vo = ((size_t)((b * 16 + hq + hh) * 64 + d)) * SS + s0g + rh * 64 + sc;
      *(bf16x8*)(Vt + vo) = v0;
      *(bf16x8*)(Vt + vo + 8) = v1;
    }
  }
}

// ---------------- K5: C[M,N] = A[M,K] @ B[N,K]^T (f32 out, for Wo) ----------------
__global__ void __launch_bounds__(256) gemm_bt_kernel(const bf16* __restrict__ A,
                                                      const bf16* __restrict__ Bm,
                                                      float* __restrict__ Cout,
                                                      int M, int N, int K) {
  __shared__ bf16 Ab[128 * 32];
  __shared__ bf16 Bb[128 * 32];
  const int tid = threadIdx.x;
  const int wid = tid >> 6, lane = tid & 63;
  const int lr = lane & 15, lg = lane >> 4;
  const int nx = N >> 7;
  const int cpx = gridDim.x >> 3;
  const int lid = (blockIdx.x & 7) * cpx + (blockIdx.x >> 3);
  const int m0 = (lid / nx) * 128, n0 = (lid % nx) * 128;
  const int wm = (wid >> 1) * 64, wn = (wid & 1) * 64;
  f32x4 acc[4][4] = {};
  for (int k0 = 0; k0 < K; k0 += 32) {
    __syncthreads();
#pragma unroll
    for (int i = 0; i < 2; ++i) {
      int o = (wid * 2 + i) * 1024 + lane * 16;
      int row = o >> 6;
      int ke = (o & 63) >> 1;
      gload_lds16(A + (size_t)(m0 + row) * K + k0 + ke, (char*)Ab + o);
      gload_lds16(Bm + (size_t)(n0 + row) * K + k0 + ke, (char*)Bb + o);
    }
    __syncthreads();
    bf16x8 af[4], bf_[4];
#pragma unroll
    for (int i = 0; i < 4; ++i) af[i] = *(const bf16x8*)&Ab[(wm + i * 16 + lr) * 32 + lg * 8];
#pragma unroll
    for (int j = 0; j < 4; ++j) bf_[j] = *(const bf16x8*)&Bb[(wn + j * 16 + lr) * 32 + lg * 8];
#pragma unroll
    for (int i = 0; i < 4; ++i)
#pragma unroll
      for (int j = 0; j < 4; ++j)
        acc[i][j] = __builtin_amdgcn_mfma_f32_16x16x32_bf16(af[i], bf_[j], acc[i][j], 0, 0, 0);
  }
#pragma unroll
  for (int i = 0; i < 4; ++i)
#pragma unroll
    for (int j = 0; j < 4; ++j)
#pragma unroll
      for (int r = 0; r < 4; ++r) {
        int row = m0 + wm + i * 16 + lg * 4 + r;
        int col = n0 + wn + j * 16 + lr;
        Cout[(size_t)row * N + col] = acc[i][j][r];
      }
}

// ---------------- K4: causal flash attention, wave-paired 64-row strips ----------------
// bh = bid&63, px = bid>>6: co-resident blocks on a CU share bh (K/V cache-hot)
// with px spread {p,p+4,p+8,p+12}; XCD = bid&7 = bh&7 (per-head KV stays in one L2).
// Block = 4 waves; wave owns 16 q-rows of strip A (xA=31-px) and 16 of strip B (xB=px)
// -> 33 compute units/block uniform. Counted-vmcnt V pipeline, defer-max softmax.
__global__ void __launch_bounds__(256, 2) flash_kernel(
    const bf16* __restrict__ Qp, const bf16* __restrict__ Kp, const bf16* __restrict__ Vt,
    bf16* __restrict__ O, const int* __restrict__ nm) {
  __shared__ bf16 Kb[2][64 * 64];
  __shared__ bf16 Vb[64 * 64];
  __shared__ u32 Pl[4][16][36];
  const int bh = blockIdx.x & 63;
  const int px = blockIdx.x >> 6;  // 0..15
  const int xA = 31 - px, xB = px;
  const int b = bh >> 4, h = bh & 15;
  const int tid = threadIdx.x;
  const int wid = tid >> 6, lane = tid & 63;
  const int lr = lane & 15, lg = lane >> 4;
  const int nmb = nm[b];
  const int wqA = xA * 64 + wid * 16;
  const int wqB = xB * 64 + wid * 16;
  const int nt = xA + 1;  // strip A is the deeper one

  bf16x8 qfA[2], qfB[2];
#pragma unroll
  for (int kh = 0; kh < 2; ++kh) {
    qfA[kh] = *(const bf16x8*)(Qp + ((size_t)bh * SS + wqA + lr) * 64 + kh * 32 + lg * 8);
    qfB[kh] = *(const bf16x8*)(Qp + ((size_t)bh * SS + wqB + lr) * 64 + kh * 32 + lg * 8);
  }

  float mA = -1e30f, lA = 0.f, mB = -1e30f, lB = 0.f;
  f32x4 oA[4] = {}, oB[4] = {};

  auto STAGE_K = [&](int bi, int t) {
    const int kv0 = t * 64;
#pragma unroll
    for (int i = 0; i < 2; ++i) {
      int o = i * 4096 + tid * 16;
      int row = o >> 7;
      int c16 = ((o >> 4) & 7) ^ (row & 7);
      gload_lds16(Kp + ((size_t)bh * SS + kv0 + row) * 64 + c16 * 8, (char*)Kb[bi] + o);
    }
  };
  auto STAGE_V = [&](int t) {
    const int kv0 = t * 64;
#pragma unroll
    for (int i = 0; i < 2; ++i) {
      int o = i * 4096 + tid * 16;
      int row = o >> 7;
      int c16 = ((o >> 4) & 7) ^ (row & 7);
      gload_lds16(Vt + ((size_t)bh * 64 + row) * SS + kv0 + c16 * 8, (char*)Vb + o);
    }
  };

  STAGE_K(0, 0);
  STAGE_V(0);
  __syncthreads();
  int buf = 0;
  for (int t = 0; t < nt; ++t) {
    const int kv0 = t * 64;
    if (t + 1 < nt) STAGE_K(buf ^ 1, t + 1);  // stays in flight across V-barrier
    const bool actB = (t <= xB);
    bf16x8 pbA[2], pbB[2];

    auto DO_STRIP = [&](const bf16x8* qf, float& m_r, float& l_pp, f32x4* oacc,
                        bf16x8* pb, int xS, int wqS) {
      f32x4 s[4];
      __builtin_amdgcn_s_setprio(1);
#pragma unroll
      for (int j = 0; j < 4; ++j) {
        int row = j * 16 + lr;
        const char* kbase = (const char*)Kb[buf] + row * 128;
        bf16x8 kf0 = *(const bf16x8*)(kbase + ((lg ^ (row & 7)) << 4));
        bf16x8 kf1 = *(const bf16x8*)(kbase + (((4 + lg) ^ (row & 7)) << 4));
        f32x4 z = {};
        z = __builtin_amdgcn_mfma_f32_16x16x32_bf16(kf0, qf[0], z, 0, 0, 0);
        z = __builtin_amdgcn_mfma_f32_16x16x32_bf16(kf1, qf[1], z, 0, 0, 0);
        s[j] = z;
      }
      __builtin_amdgcn_s_setprio(0);
      if (t == xS) {  // causal boundary tile
        int qr = wqS + lr;
#pragma unroll
        for (int j = 0; j < 4; ++j) {
          int kvb = kv0 + j * 16 + lg * 4;
#pragma unroll
          for (int r = 0; r < 4; ++r)
            if (kvb + r > qr) s[j][r] = -1e30f;
        }
      }
      if (kv0 < nmb) {  // prefix-padding mask
#pragma unroll
        for (int j = 0; j < 4; ++j) {
          int kvb = kv0 + j * 16 + lg * 4;
#pragma unroll
          for (int r = 0; r < 4; ++r)
            if (kvb + r < nmb) s[j][r] = -1e30f;
        }
      }
      float pm0 = fmaxf(fmaxf(s[0][0], s[0][1]), fmaxf(s[0][2], s[0][3]));
      float pm1 = fmaxf(fmaxf(s[1][0], s[1][1]), fmaxf(s[1][2], s[1][3]));
      float pm2 = fmaxf(fmaxf(s[2][0], s[2][1]), fmaxf(s[2][2], s[2][3]));
      float pm3 = fmaxf(fmaxf(s[3][0], s[3][1]), fmaxf(s[3][2], s[3][3]));
      float pm = fmaxf(fmaxf(pm0, pm1), fmaxf(pm2, pm3));
      if (!__all(pm - m_r <= 8.f)) {  // defer-max (exp2 domain, THR=8)
        pm = fmaxf(pm, __shfl_xor(pm, 16));
        pm = fmaxf(pm, __shfl_xor(pm, 32));
        float mn = fmaxf(m_r, pm);
        float scl = exp2f(m_r - mn);
        m_r = mn;
        l_pp *= scl;
        f32x4 sv = {scl, scl, scl, scl};
#pragma unroll
        for (int jd = 0; jd < 4; ++jd) oacc[jd] *= sv;
      }
      const float mloc = m_r;
      float lp = l_pp;
#pragma unroll
      for (int j = 0; j < 4; ++j) {
        float p0 = exp2f(s[j][0] - mloc), p1 = exp2f(s[j][1] - mloc);
        float p2 = exp2f(s[j][2] - mloc), p3 = exp2f(s[j][3] - mloc);
        lp += (p0 + p1) + (p2 + p3);
        union { bf16 hx[4]; uint2 u2; } pk;  // compiler emits packed cvt (m240)
        pk.hx[0] = (bf16)p0; pk.hx[1] = (bf16)p1;
        pk.hx[2] = (bf16)p2; pk.hx[3] = (bf16)p3;
        *(uint2*)&Pl[wid][lr][j * 8 + lg * 2] = pk.u2;
      }
      l_pp = lp;
#pragma unroll
      for (int kh = 0; kh < 2; ++kh) pb[kh] = *(const bf16x8*)&Pl[wid][lr][kh * 16 + lg * 4];
    };

    DO_STRIP(qfA, mA, lA, oA, pbA, xA, wqA);
    if (actB) DO_STRIP(qfB, mB, lB, oB, pbB, xB, wqB);

    // ---- V[t] visibility (K[t+1] stays in flight) ----
    if (t > 0) {
      if (t + 1 < nt)
        asm volatile("s_waitcnt vmcnt(2)" ::: "memory");
      else
        asm volatile("s_waitcnt vmcnt(0)" ::: "memory");
      __builtin_amdgcn_s_barrier();
      __builtin_amdgcn_sched_barrier(0);
    }
    __builtin_amdgcn_s_setprio(1);
#pragma unroll
    for (int jd = 0; jd < 4; ++jd) {
      int row = jd * 16 + lr;
      const char* vbase = (const char*)Vb + row * 128;
      bf16x8 va0 = *(const bf16x8*)(vbase + ((lg ^ (row & 7)) << 4));
      bf16x8 va1 = *(const bf16x8*)(vbase + (((4 + lg) ^ (row & 7)) << 4));
      oA[jd] = __builtin_amdgcn_mfma_f32_16x16x32_bf16(va0, pbA[0], oA[jd], 0, 0, 0);
      oA[jd] = __builtin_amdgcn_mfma_f32_16x16x32_bf16(va1, pbA[1], oA[jd], 0, 0, 0);
      if (actB) {
        oB[jd] = __builtin_amdgcn_mfma_f32_16x16x32_bf16(va0, pbB[0], oB[jd], 0, 0, 0);
        oB[jd] = __builtin_amdgcn_mfma_f32_16x16x32_bf16(va1, pbB[1], oB[jd], 0, 0, 0);
      }
    }
    __builtin_amdgcn_s_setprio(0);
    __syncthreads();  // all waves done with Vb (and Kb[buf])
    if (t + 1 < nt) STAGE_V(t + 1);
    buf ^= 1;
  }
  // ---- epilogue ----
#pragma unroll
  for (int st = 0; st < 2; ++st) {
    float l = st == 0 ? lA : lB;
    const f32x4* oacc = st == 0 ? oA : oB;
    int wq = st == 0 ? wqA : wqB;
    l += __shfl_xor(l, 16);
    l += __shfl_xor(l, 32);
    float invl = 1.0f / l;
    size_t rowoff = ((size_t)b * SS + wq + lr) * DD + h * 64;
#pragma unroll
    for (int jd = 0; jd < 4; ++jd) {
      f32x4 ov = oacc[jd] * invl;
      bf16x4 hv;
      hv[0] = (bf16)ov[0]; hv[1] = (bf16)ov[1]; hv[2] = (bf16)ov[2]; hv[3] = (bf16)ov[3];
      *(bf16x4*)(O + rowoff + jd * 16 + lg * 4) = hv;
    }
  }
}

// ---------------- host launch ----------------
extern "C" void kernel_launch(void* const* d_in, const int* in_sizes, int n_in,
                              void* d_out, int out_size, void* d_ws, size_t ws_size,
                              hipStream_t stream) {
  const float* X = (const float*)d_in[0];
  const float* Wq = (const float*)d_in[1];
  const float* Wk = (const float*)d_in[2];
  const float* Wv = (const float*)d_in[3];
  const float* Wo = (const float*)d_in[4];
  const float* qls = (const float*)d_in[5];
  const float* kls = (const float*)d_in[6];
  const float* pds = (const float*)d_in[7];
  const unsigned char* mask = (const unsigned char*)d_in[8];

  char* ws = (char*)d_ws;
  size_t off = 0;
  auto alloc = [&](size_t bytes) {
    char* p = ws + off;
    off += (bytes + 255) & ~(size_t)255;
    return p;
  };
  const size_t NTOK = (size_t)BB * SS;  // 8192
  int* nm = (int*)alloc(16);
  bf16* Xb = (bf16*)alloc(NTOK * DD * 2);
  bf16* Wqb = (bf16*)alloc((size_t)DD * DD * 2);
  bf16* Wkb = (bf16*)alloc((size_t)DD * DD * 2);
  bf16* Wvb = (bf16*)alloc((size_t)DD * DD * 2);
  bf16* Wob = (bf16*)alloc((size_t)DD * DD * 2);
  bf16* Qp = (bf16*)alloc(NTOK * DD * 2);
  bf16* Kp = (bf16*)alloc(NTOK * DD * 2);
  bf16* Vt = (bf16*)alloc(NTOK * DD * 2);
  float2* tbl = (float2*)alloc(NTOK * 32 * sizeof(float2));
  bf16* Oat = Xb;  // alias: Xb dead after fused QKV GEMM

  mask_count_kernel<<<1, 256, 0, stream>>>(mask, nm);
  cvt_kernel<<<1024, 256, 0, stream>>>(X, Xb, (int)(NTOK * DD / 4));
  cvt_kernel<<<256, 256, 0, stream>>>(Wq, Wqb, DD * DD / 4);
  cvt_kernel<<<256, 256, 0, stream>>>(Wk, Wkb, DD * DD / 4);
  cvt_kernel<<<256, 256, 0, stream>>>(Wv, Wvb, DD * DD / 4);
  cvt_kernel<<<256, 256, 0, stream>>>(Wo, Wob, DD * DD / 4);
  sincos_table_kernel<<<32, 256, 0, stream>>>(nm, tbl);

  gemm_qkv_kernel<<<(int)(NTOK / 128) * 24, 256, 0, stream>>>(Xb, Wqb, Wkb, Wvb, qls, kls, pds,
                                                              tbl, Qp, Kp, Vt);
  flash_kernel<<<1024, 256, 0, stream>>>(Qp, Kp, Vt, Oat, nm);
  gemm_bt_kernel<<<(int)(NTOK / 128) * (DD / 128), 256, 0, stream>>>(Oat, Wob, (float*)d_out,
                                                                     (int)NTOK, DD, DD);
}

// Round 8
// 199.765 us; speedup vs baseline: 1.6350x; 1.0208x over previous
//
#include <hip/hip_runtime.h>
#include <cstdint>
#include <cstddef>

#define BB 4
#define SS 2048
#define DD 1024
#define HH 16

typedef __bf16 bf16;
typedef __bf16 bf16x8 __attribute__((ext_vector_type(8)));
typedef __bf16 bf16x4 __attribute__((ext_vector_type(4)));
typedef float f32x4 __attribute__((ext_vector_type(4)));
typedef unsigned int u32;

typedef __attribute__((address_space(1))) const void* as1_cvoid;
typedef __attribute__((address_space(3))) void* as3_void;

__device__ __forceinline__ void gload_lds16(const void* g, void* l) {
  __builtin_amdgcn_global_load_lds((as1_cvoid)g, (as3_void)l, 16, 0, 0);
}

// ---------------- K0: per-batch masked count ----------------
__global__ void mask_count_kernel(const unsigned char* __restrict__ mask, int* __restrict__ nm) {
  int wid = threadIdx.x >> 6, lane = threadIdx.x & 63;
  if (wid >= BB) return;
  int s = 0;
  for (int i = lane; i < SS; i += 64) s += (mask[wid * SS + i] != 0) ? 1 : 0;
#pragma unroll
  for (int m = 1; m < 64; m <<= 1) s += __shfl_xor(s, m);
  if (lane == 0) nm[wid] = s;
}

// ---------------- K1: f32 -> bf16 convert ----------------
__global__ void cvt_kernel(const float* __restrict__ src, bf16* __restrict__ dst, int n4) {
  int stride = gridDim.x * blockDim.x;
  for (int i = blockIdx.x * blockDim.x + threadIdx.x; i < n4; i += stride) {
    float4 v = ((const float4*)src)[i];
    bf16x4 o;
    o[0] = (bf16)v.x; o[1] = (bf16)v.y; o[2] = (bf16)v.z; o[3] = (bf16)v.w;
    ((bf16x4*)dst)[i] = o;
  }
}

// ---------------- K1b: RoPE sin/cos table: tbl[(b*S+s)*32+j] = (cos,sin) ----------------
__global__ void sincos_table_kernel(const int* __restrict__ nm, float2* __restrict__ tbl) {
  int g = blockIdx.x * 256 + threadIdx.x;  // (b*S+s)*32 + j, 262144 total
  int j = g & 31;
  int idx = g >> 5;
  int b = idx >> 11, s = idx & 2047;
  int pos = s - nm[b];
  float inv_ts = __expf((float)j * (-9.210340371976184f / 32.0f));  // 10000^{-j/32}
  float sn, cs;
  sincosf((float)pos * inv_ts, &sn, &cs);
  tbl[g] = make_float2(cs, sn);
}

// ---------------- K2: fused QKV GEMM + RoPE/RMS/scale epilogue ----------------
__global__ void __launch_bounds__(256) gemm_qkv_kernel(
    const bf16* __restrict__ A, const bf16* __restrict__ Wq, const bf16* __restrict__ Wk,
    const bf16* __restrict__ Wv, const float* __restrict__ qls, const float* __restrict__ kls,
    const float* __restrict__ pds, const float2* __restrict__ tbl,
    bf16* __restrict__ Qp, bf16* __restrict__ Kp, bf16* __restrict__ Vt) {
  __shared__ __align__(16) char smem[4 * 64 * 72 * 2];  // staging (16K) U transpose (36K)
  bf16* Ab = (bf16*)smem;
  bf16* Bb = (bf16*)(smem + 8192);
  const int tid = threadIdx.x;
  const int wid = tid >> 6, lane = tid & 63;
  const int lr = lane & 15, lg = lane >> 4;
  const int K = DD;
  const int nx = 24;  // 3 matrices x 8 N-tiles
  const int cpx = gridDim.x >> 3;
  const int lid = (blockIdx.x & 7) * cpx + (blockIdx.x >> 3);
  const int m0 = (lid / nx) * 128;
  const int ntile = lid % nx;
  const int which = ntile >> 3;
  const int n0 = (ntile & 7) * 128;
  const bf16* Bm = which == 0 ? Wq : (which == 1 ? Wk : Wv);
  const int wm = (wid >> 1) * 64, wn = (wid & 1) * 64;
  f32x4 acc[4][4] = {};
  for (int k0 = 0; k0 < K; k0 += 32) {
    __syncthreads();
#pragma unroll
    for (int i = 0; i < 2; ++i) {
      int o = (wid * 2 + i) * 1024 + lane * 16;
      int row = o >> 6;
      int ke = (o & 63) >> 1;
      gload_lds16(A + (size_t)(m0 + row) * K + k0 + ke, (char*)Ab + o);
      gload_lds16(Bm + (size_t)(n0 + row) * K + k0 + ke, (char*)Bb + o);
    }
    __syncthreads();
    bf16x8 af[4], bf_[4];
#pragma unroll
    for (int i = 0; i < 4; ++i) af[i] = *(const bf16x8*)&Ab[(wm + i * 16 + lr) * 32 + lg * 8];
#pragma unroll
    for (int j = 0; j < 4; ++j) bf_[j] = *(const bf16x8*)&Bb[(wn + j * 16 + lr) * 32 + lg * 8];
#pragma unroll
    for (int i = 0; i < 4; ++i)
#pragma unroll
      for (int j = 0; j < 4; ++j)
        acc[i][j] = __builtin_amdgcn_mfma_f32_16x16x32_bf16(af[i], bf_[j], acc[i][j], 0, 0, 0);
  }
  const int b = m0 >> 11;
  const int s0g = m0 & 2047;
  const int hq = n0 >> 6;  // first of 2 heads in this N-tile
  if (which < 2) {
    // ---- Q/K epilogue: rope -> rms -> scale, write [B,H,S,64] ----
    float scj[4];
#pragma unroll
    for (int j = 0; j < 4; ++j) {
      int d = j * 16 + lr;
      scj[j] = (which == 0) ? qls[d] * 0.26017112262570096f * log1pf(__expf(pds[d]))
                            : kls[d];
    }
    bf16* Out = which == 0 ? Qp : Kp;
    const int h = hq + (wn >> 6);
    const size_t base = (size_t)(b * 16 + h) * SS;
#pragma unroll
    for (int i = 0; i < 4; ++i)
#pragma unroll
      for (int r = 0; r < 4; ++r) {
        int srow = s0g + wm + i * 16 + lg * 4 + r;
        const float2* trow = tbl + ((size_t)(b * SS + srow) << 5);
        float2 t0 = trow[lr], t1 = trow[16 + lr];
        float a0 = acc[i][0][r], a1 = acc[i][1][r], a2 = acc[i][2][r], a3 = acc[i][3][r];
        float n0_ = a0 * t0.x - a2 * t0.y;
        float n2_ = a2 * t0.x + a0 * t0.y;
        float n1_ = a1 * t1.x - a3 * t1.y;
        float n3_ = a3 * t1.x + a1 * t1.y;
        float ssum = n0_ * n0_ + n1_ * n1_ + n2_ * n2_ + n3_ * n3_;
        ssum += __shfl_xor(ssum, 1);
        ssum += __shfl_xor(ssum, 2);
        ssum += __shfl_xor(ssum, 4);
        ssum += __shfl_xor(ssum, 8);
        float rinv = rsqrtf(ssum * (1.0f / 64.0f) + 1e-6f);
        bf16* orow = Out + (base + srow) * 64;
        orow[lr]      = (bf16)(n0_ * rinv * scj[0]);
        orow[16 + lr] = (bf16)(n1_ * rinv * scj[1]);
        orow[32 + lr] = (bf16)(n2_ * rinv * scj[2]);
        orow[48 + lr] = (bf16)(n3_ * rinv * scj[3]);
      }
  } else {
    // ---- V epilogue: transpose via LDS (reuse staging region), write [B,H,64,S] ----
    __syncthreads();  // all MFMA LDS reads done; safe to reuse smem
    bf16* tw = (bf16*)smem + wid * 64 * 72;  // per-wave [64 d][72 s-padded]
#pragma unroll
    for (int i = 0; i < 4; ++i)
#pragma unroll
      for (int j = 0; j < 4; ++j)
#pragma unroll
        for (int r = 0; r < 4; ++r)
          tw[(j * 16 + lr) * 72 + i * 16 + lg * 4 + r] = (bf16)acc[i][j][r];
    __syncthreads();
    int d = tid >> 2, sc = (tid & 3) * 16;
#pragma unroll
    for (int w = 0; w < 4; ++w) {
      int rh = w >> 1, hh = w & 1;
      const bf16* ts = (const bf16*)smem + w * 64 * 72 + d * 72 + sc;
      bf16x8 v0 = *(const bf16x8*)ts;
      bf16x8 v1 = *(const bf16x8*)(ts + 8);
      size_t vo = ((size_t)((b * 16 + hq + hh) * 64 + d)) * SS + s0g + rh * 64 + sc;
      *(bf16x8*)(Vt + vo) = v0;
      *(bf16x8*)(Vt + vo + 8) = v1;
    }
  }
}

// ---------------- K5: C[M,N] = A[M,K] @ B[N,K]^T (f32 out, for Wo) ----------------
__global__ void __launch_bounds__(256) gemm_bt_kernel(const bf16* __restrict__ A,
                                                      const bf16* __restrict__ Bm,
                                                      float* __restrict__ Cout,
                                                      int M, int N, int K) {
  __shared__ bf16 Ab[128 * 32];
  __shared__ bf16 Bb[128 * 32];
  const int tid = threadIdx.x;
  const int wid = tid >> 6, lane = tid & 63;
  const int lr = lane & 15, lg = lane >> 4;
  const int nx = N >> 7;
  const int cpx = gridDim.x >> 3;
  const int lid = (blockIdx.x & 7) * cpx + (blockIdx.x >> 3);
  const int m0 = (lid / nx) * 128, n0 = (lid % nx) * 128;
  const int wm = (wid >> 1) * 64, wn = (wid & 1) * 64;
  f32x4 acc[4][4] = {};
  for (int k0 = 0; k0 < K; k0 += 32) {
    __syncthreads();
#pragma unroll
    for (int i = 0; i < 2; ++i) {
      int o = (wid * 2 + i) * 1024 + lane * 16;
      int row = o >> 6;
      int ke = (o & 63) >> 1;
      gload_lds16(A + (size_t)(m0 + row) * K + k0 + ke, (char*)Ab + o);
      gload_lds16(Bm + (size_t)(n0 + row) * K + k0 + ke, (char*)Bb + o);
    }
    __syncthreads();
    bf16x8 af[4], bf_[4];
#pragma unroll
    for (int i = 0; i < 4; ++i) af[i] = *(const bf16x8*)&Ab[(wm + i * 16 + lr) * 32 + lg * 8];
#pragma unroll
    for (int j = 0; j < 4; ++j) bf_[j] = *(const bf16x8*)&Bb[(wn + j * 16 + lr) * 32 + lg * 8];
#pragma unroll
    for (int i = 0; i < 4; ++i)
#pragma unroll
      for (int j = 0; j < 4; ++j)
        acc[i][j] = __builtin_amdgcn_mfma_f32_16x16x32_bf16(af[i], bf_[j], acc[i][j], 0, 0, 0);
  }
#pragma unroll
  for (int i = 0; i < 4; ++i)
#pragma unroll
    for (int j = 0; j < 4; ++j)
#pragma unroll
      for (int r = 0; r < 4; ++r) {
        int row = m0 + wm + i * 16 + lg * 4 + r;
        int col = n0 + wn + j * 16 + lr;
        Cout[(size_t)row * N + col] = acc[i][j][r];
      }
}

// ---------------- K4: causal flash attention, wave-paired strips, fused QK^T ----------------
// bh = bid&63, px = bid>>6. Per tile: ONE pass over Kb reads kf fragments and issues
// MFMA for both strips (halves ds_read_b128 + address VALU vs per-strip QK), then
// per-strip in-register softmax (max3 tree, defer-max), P via per-wave LDS, shared-Vb PV.
__global__ void __launch_bounds__(256, 2) flash_kernel(
    const bf16* __restrict__ Qp, const bf16* __restrict__ Kp, const bf16* __restrict__ Vt,
    bf16* __restrict__ O, const int* __restrict__ nm) {
  __shared__ bf16 Kb[2][64 * 64];
  __shared__ bf16 Vb[64 * 64];
  __shared__ u32 Pl[4][16][36];
  const int bh = blockIdx.x & 63;
  const int px = blockIdx.x >> 6;  // 0..15
  const int xA = 31 - px, xB = px;
  const int b = bh >> 4, h = bh & 15;
  const int tid = threadIdx.x;
  const int wid = tid >> 6, lane = tid & 63;
  const int lr = lane & 15, lg = lane >> 4;
  const int nmb = nm[b];
  const int wqA = xA * 64 + wid * 16;
  const int wqB = xB * 64 + wid * 16;
  const int nt = xA + 1;  // strip A is the deeper one

  bf16x8 qfA[2], qfB[2];
#pragma unroll
  for (int kh = 0; kh < 2; ++kh) {
    qfA[kh] = *(const bf16x8*)(Qp + ((size_t)bh * SS + wqA + lr) * 64 + kh * 32 + lg * 8);
    qfB[kh] = *(const bf16x8*)(Qp + ((size_t)bh * SS + wqB + lr) * 64 + kh * 32 + lg * 8);
  }

  float mA = -1e30f, lA = 0.f, mB = -1e30f, lB = 0.f;
  f32x4 oA[4] = {}, oB[4] = {};

  auto STAGE_K = [&](int bi, int t) {
    const int kv0 = t * 64;
#pragma unroll
    for (int i = 0; i < 2; ++i) {
      int o = i * 4096 + tid * 16;
      int row = o >> 7;
      int c16 = ((o >> 4) & 7) ^ (row & 7);
      gload_lds16(Kp + ((size_t)bh * SS + kv0 + row) * 64 + c16 * 8, (char*)Kb[bi] + o);
    }
  };
  auto STAGE_V = [&](int t) {
    const int kv0 = t * 64;
#pragma unroll
    for (int i = 0; i < 2; ++i) {
      int o = i * 4096 + tid * 16;
      int row = o >> 7;
      int c16 = ((o >> 4) & 7) ^ (row & 7);
      gload_lds16(Vt + ((size_t)bh * 64 + row) * SS + kv0 + c16 * 8, (char*)Vb + o);
    }
  };

  STAGE_K(0, 0);
  STAGE_V(0);
  __syncthreads();
  int buf = 0;
  for (int t = 0; t < nt; ++t) {
    const int kv0 = t * 64;
    if (t + 1 < nt) STAGE_K(buf ^ 1, t + 1);  // stays in flight across V-barrier
    const bool actB = (t <= xB);
    bf16x8 pbA[2], pbB[2];
    f32x4 sA[4], sB[4];

    // ---- fused QK^T: one pass over Kb serves both strips ----
    __builtin_amdgcn_s_setprio(1);
#pragma unroll
    for (int j = 0; j < 4; ++j) {
      int row = j * 16 + lr;
      const char* kbase = (const char*)Kb[buf] + row * 128;
      bf16x8 kf0 = *(const bf16x8*)(kbase + ((lg ^ (row & 7)) << 4));
      bf16x8 kf1 = *(const bf16x8*)(kbase + (((4 + lg) ^ (row & 7)) << 4));
      f32x4 z = {};
      z = __builtin_amdgcn_mfma_f32_16x16x32_bf16(kf0, qfA[0], z, 0, 0, 0);
      z = __builtin_amdgcn_mfma_f32_16x16x32_bf16(kf1, qfA[1], z, 0, 0, 0);
      sA[j] = z;
      if (actB) {
        f32x4 z2 = {};
        z2 = __builtin_amdgcn_mfma_f32_16x16x32_bf16(kf0, qfB[0], z2, 0, 0, 0);
        z2 = __builtin_amdgcn_mfma_f32_16x16x32_bf16(kf1, qfB[1], z2, 0, 0, 0);
        sB[j] = z2;
      }
    }
    __builtin_amdgcn_s_setprio(0);

    auto SOFTMAX = [&](f32x4* s, float& m_r, float& l_pp, f32x4* oacc, bf16x8* pb,
                       int xS, int wqS) {
      if (t == xS) {  // causal boundary tile
        int qr = wqS + lr;
#pragma unroll
        for (int j = 0; j < 4; ++j) {
          int kvb = kv0 + j * 16 + lg * 4;
#pragma unroll
          for (int r = 0; r < 4; ++r)
            if (kvb + r > qr) s[j][r] = -1e30f;
        }
      }
      if (kv0 < nmb) {  // prefix-padding mask
#pragma unroll
        for (int j = 0; j < 4; ++j) {
          int kvb = kv0 + j * 16 + lg * 4;
#pragma unroll
          for (int r = 0; r < 4; ++r)
            if (kvb + r < nmb) s[j][r] = -1e30f;
        }
      }
      // max3-friendly reduction (8 instrs for 16 values)
      float t0 = fmaxf(fmaxf(s[0][0], s[0][1]), s[0][2]);
      float t1 = fmaxf(fmaxf(s[0][3], s[1][0]), s[1][1]);
      float t2 = fmaxf(fmaxf(s[1][2], s[1][3]), s[2][0]);
      float t3 = fmaxf(fmaxf(s[2][1], s[2][2]), s[2][3]);
      float t4 = fmaxf(fmaxf(s[3][0], s[3][1]), s[3][2]);
      float t5 = fmaxf(fmaxf(t0, t1), s[3][3]);
      float pm = fmaxf(fmaxf(t2, t3), fmaxf(t4, t5));
      if (!__all(pm - m_r <= 8.f)) {  // defer-max (exp2 domain, THR=8)
        pm = fmaxf(pm, __shfl_xor(pm, 16));
        pm = fmaxf(pm, __shfl_xor(pm, 32));
        float mn = fmaxf(m_r, pm);
        float scl = exp2f(m_r - mn);
        m_r = mn;
        l_pp *= scl;
        f32x4 sv = {scl, scl, scl, scl};
#pragma unroll
        for (int jd = 0; jd < 4; ++jd) oacc[jd] *= sv;
      }
      const float mloc = m_r;
      float lp = l_pp;
#pragma unroll
      for (int j = 0; j < 4; ++j) {
        float p0 = exp2f(s[j][0] - mloc), p1 = exp2f(s[j][1] - mloc);
        float p2 = exp2f(s[j][2] - mloc), p3 = exp2f(s[j][3] - mloc);
        lp += (p0 + p1) + (p2 + p3);
        union { bf16 hx[4]; uint2 u2; } pk;
        pk.hx[0] = (bf16)p0; pk.hx[1] = (bf16)p1;
        pk.hx[2] = (bf16)p2; pk.hx[3] = (bf16)p3;
        *(uint2*)&Pl[wid][lr][j * 8 + lg * 2] = pk.u2;
      }
      l_pp = lp;
#pragma unroll
      for (int kh = 0; kh < 2; ++kh) pb[kh] = *(const bf16x8*)&Pl[wid][lr][kh * 16 + lg * 4];
    };

    SOFTMAX(sA, mA, lA, oA, pbA, xA, wqA);
    if (actB) SOFTMAX(sB, mB, lB, oB, pbB, xB, wqB);

    // ---- V[t] visibility (K[t+1] stays in flight) ----
    if (t > 0) {
      if (t + 1 < nt)
        asm volatile("s_waitcnt vmcnt(2)" ::: "memory");
      else
        asm volatile("s_waitcnt vmcnt(0)" ::: "memory");
      __builtin_amdgcn_s_barrier();
      __builtin_amdgcn_sched_barrier(0);
    }
    __builtin_amdgcn_s_setprio(1);
#pragma unroll
    for (int jd = 0; jd < 4; ++jd) {
      int row = jd * 16 + lr;
      const char* vbase = (const char*)Vb + row * 128;
      bf16x8 va0 = *(const bf16x8*)(vbase + ((lg ^ (row & 7)) << 4));
      bf16x8 va1 = *(const bf16x8*)(vbase + (((4 + lg) ^ (row & 7)) << 4));
      oA[jd] = __builtin_amdgcn_mfma_f32_16x16x32_bf16(va0, pbA[0], oA[jd], 0, 0, 0);
      oA[jd] = __builtin_amdgcn_mfma_f32_16x16x32_bf16(va1, pbA[1], oA[jd], 0, 0, 0);
      if (actB) {
        oB[jd] = __builtin_amdgcn_mfma_f32_16x16x32_bf16(va0, pbB[0], oB[jd], 0, 0, 0);
        oB[jd] = __builtin_amdgcn_mfma_f32_16x16x32_bf16(va1, pbB[1], oB[jd], 0, 0, 0);
      }
    }
    __builtin_amdgcn_s_setprio(0);
    __syncthreads();  // all waves done with Vb (and Kb[buf])
    if (t + 1 < nt) STAGE_V(t + 1);
    buf ^= 1;
  }
  // ---- epilogue ----
#pragma unroll
  for (int st = 0; st < 2; ++st) {
    float l = st == 0 ? lA : lB;
    const f32x4* oacc = st == 0 ? oA : oB;
    int wq = st == 0 ? wqA : wqB;
    l += __shfl_xor(l, 16);
    l += __shfl_xor(l, 32);
    float invl = 1.0f / l;
    size_t rowoff = ((size_t)b * SS + wq + lr) * DD + h * 64;
#pragma unroll
    for (int jd = 0; jd < 4; ++jd) {
      f32x4 ov = oacc[jd] * invl;
      bf16x4 hv;
      hv[0] = (bf16)ov[0]; hv[1] = (bf16)ov[1]; hv[2] = (bf16)ov[2]; hv[3] = (bf16)ov[3];
      *(bf16x4*)(O + rowoff + jd * 16 + lg * 4) = hv;
    }
  }
}

// ---------------- host launch ----------------
extern "C" void kernel_launch(void* const* d_in, const int* in_sizes, int n_in,
                              void* d_out, int out_size, void* d_ws, size_t ws_size,
                              hipStream_t stream) {
  const float* X = (const float*)d_in[0];
  const float* Wq = (const float*)d_in[1];
  const float* Wk = (const float*)d_in[2];
  const float* Wv = (const float*)d_in[3];
  const float* Wo = (const float*)d_in[4];
  const float* qls = (const float*)d_in[5];
  const float* kls = (const float*)d_in[6];
  const float* pds = (const float*)d_in[7];
  const unsigned char* mask = (const unsigned char*)d_in[8];

  char* ws = (char*)d_ws;
  size_t off = 0;
  auto alloc = [&](size_t bytes) {
    char* p = ws + off;
    off += (bytes + 255) & ~(size_t)255;
    return p;
  };
  const size_t NTOK = (size_t)BB * SS;  // 8192
  int* nm = (int*)alloc(16);
  bf16* Xb = (bf16*)alloc(NTOK * DD * 2);
  bf16* Wqb = (bf16*)alloc((size_t)DD * DD * 2);
  bf16* Wkb = (bf16*)alloc((size_t)DD * DD * 2);
  bf16* Wvb = (bf16*)alloc((size_t)DD * DD * 2);
  bf16* Wob = (bf16*)alloc((size_t)DD * DD * 2);
  bf16* Qp = (bf16*)alloc(NTOK * DD * 2);
  bf16* Kp = (bf16*)alloc(NTOK * DD * 2);
  bf16* Vt = (bf16*)alloc(NTOK * DD * 2);
  float2* tbl = (float2*)alloc(NTOK * 32 * sizeof(float2));
  bf16* Oat = Xb;  // alias: Xb dead after fused QKV GEMM

  mask_count_kernel<<<1, 256, 0, stream>>>(mask, nm);
  cvt_kernel<<<1024, 256, 0, stream>>>(X, Xb, (int)(NTOK * DD / 4));
  cvt_kernel<<<256, 256, 0, stream>>>(Wq, Wqb, DD * DD / 4);
  cvt_kernel<<<256, 256, 0, stream>>>(Wk, Wkb, DD * DD / 4);
  cvt_kernel<<<256, 256, 0, stream>>>(Wv, Wvb, DD * DD / 4);
  cvt_kernel<<<256, 256, 0, stream>>>(Wo, Wob, DD * DD / 4);
  sincos_table_kernel<<<1024, 256, 0, stream>>>(nm, tbl);

  gemm_qkv_kernel<<<(int)(NTOK / 128) * 24, 256, 0, stream>>>(Xb, Wqb, Wkb, Wvb, qls, kls, pds,
                                                              tbl, Qp, Kp, Vt);
  flash_kernel<<<1024, 256, 0, stream>>>(Qp, Kp, Vt, Oat, nm);
  gemm_bt_kernel<<<(int)(NTOK / 128) * (DD / 128), 256, 0, stream>>>(Oat, Wob, (float*)d_out,
                                                                     (int)NTOK, DD, DD);
}